// Round 7
// baseline (188.653 us; speedup 1.0000x reference)
//
#include <hip/hip_runtime.h>
#include <math.h>

#define G    64
#define NPG  2048
#define NTOT (G * NPG)          // 131072
#define EPG  (NPG * 8)          // 16384 edges per graph (contiguous by construction)
#define NE   (NTOT * 8)         // 1048576
#define KSEL 410
#define NK   (G * KSEL)         // 26240
#define NH   3
#define NC   20
#define HC   60

__device__ inline float leaky(float x) { return x >= 0.f ? x : 0.2f * x; }

__device__ inline int wave_incl_scan(int v) {
    int lane = threadIdx.x & 63;
#pragma unroll
    for (int d = 1; d < 64; d <<= 1) {
        int t = __shfl_up(v, d, 64);
        if (lane >= d) v += t;
    }
    return v;
}

// ---------------------------------------------------------------------------
// 1. Per-graph CSR build (LDS hist -> wave-shuffle scan -> scatter), fused h1.
//    1024 threads, ~48 KB LDS, 5 barriers.
// ---------------------------------------------------------------------------
__global__ __launch_bounds__(1024) void k_csr(
    const float* __restrict__ x, const int* __restrict__ src, const int* __restrict__ dst,
    const float* __restrict__ W1, float* __restrict__ h1g, float* __restrict__ dinvg,
    int* __restrict__ rowptrg, unsigned short* __restrict__ csrg)
{
    __shared__ int hist[NPG];
    __shared__ int rs[NPG];
    __shared__ unsigned short csr[EPG];
    __shared__ int wsum[16];
    int g = blockIdx.x, tid = threadIdx.x;
    int nbase = g * NPG, ebase = g * EPG;

    for (int i = tid; i < NPG; i += 1024) hist[i] = 0;
    // fused h1 = x @ W1 (independent of CSR phases)
    for (int i = tid; i < NPG; i += 1024) {
        float xi[5];
#pragma unroll
        for (int k = 0; k < 5; k++) xi[k] = x[(size_t)(nbase + i) * 5 + k];
#pragma unroll
        for (int j = 0; j < 10; j++) {
            float s = 0.f;
#pragma unroll
            for (int k = 0; k < 5; k++) s += xi[k] * W1[k * 10 + j];
            h1g[(size_t)(nbase + i) * 10 + j] = s;
        }
    }
    __syncthreads();
    for (int e = tid; e < EPG; e += 1024)
        atomicAdd(&hist[dst[ebase + e] - nbase], 1);
    __syncthreads();
    // blocked exclusive scan: 2 bins/thread, wave shuffles, 16 wave partials
    int b2 = tid * 2;
    int v0 = hist[b2], v1 = hist[b2 + 1];
    int s = v0 + v1;
    int incl = wave_incl_scan(s);
    int wid = tid >> 6;
    if ((tid & 63) == 63) wsum[wid] = incl;
    __syncthreads();
    if (tid == 0) {
        int a = 0;
#pragma unroll
        for (int w = 0; w < 16; w++) { int t = wsum[w]; wsum[w] = a; a += t; }
    }
    __syncthreads();
    int base = wsum[wid] + incl - s;
    {
        int E0 = base, E1 = base + v0;
        rs[b2] = E0;       rs[b2 + 1] = E1;
        rowptrg[nbase + b2] = ebase + E0;
        rowptrg[nbase + b2 + 1] = ebase + E1;
        dinvg[nbase + b2] = rsqrtf((float)v0 + 1.0f);
        dinvg[nbase + b2 + 1] = rsqrtf((float)v1 + 1.0f);
        hist[b2] = 0; hist[b2 + 1] = 0;      // become cursors
    }
    if (g == G - 1 && tid == 0) rowptrg[NTOT] = NE;   // sentinel
    __syncthreads();
    for (int e = tid; e < EPG; e += 1024) {
        int ee = ebase + e;
        int sl = src[ee] - nbase;
        int dl = dst[ee] - nbase;
        int pos = rs[dl] + atomicAdd(&hist[dl], 1);
        csr[pos] = (unsigned short)sl;
    }
    __syncthreads();
    {   // coalesced writeout
        const unsigned* s4 = (const unsigned*)csr;
        unsigned* d4 = (unsigned*)(csrg + ebase);
        for (int w = tid; w < EPG / 2; w += 1024) d4[w] = s4[w];
    }
}

// ---------------------------------------------------------------------------
// 2. GCN10 gather, channel-parallel: 16 threads per node (c = lane group).
//    Lanes 0..9 handle channels; csr/dinv broadcast; h1 row read contiguous.
//    hs via 16-lane shfl reduction. Zero barriers.
// ---------------------------------------------------------------------------
__global__ __launch_bounds__(256) void k_gcn10(const float* __restrict__ h1, const float* __restrict__ dinvg,
                                               const int* __restrict__ rowptrg, const unsigned short* __restrict__ csrg,
                                               const float* __restrict__ b1, const float* __restrict__ Ws,
                                               float* __restrict__ x1g, float* __restrict__ hsg) {
    int t = blockIdx.x * blockDim.x + threadIdx.x;   // < NTOT*16
    int i = t >> 4, c = t & 15;
    bool act = (c < 10);
    int nbase = i & ~(NPG - 1);
    float di = dinvg[i];
    int p0 = rowptrg[i], p1 = rowptrg[i + 1];
    float acc = 0.f;
    for (int e = p0; e < p1; e++) {
        int s = nbase + csrg[e];
        float dv = dinvg[s];
        if (act) acc += h1[(size_t)s * 10 + c] * dv;
    }
    float v = 0.f, pd = 0.f;
    if (act) {
        v = acc * di + h1[(size_t)i * 10 + c] * di * di + b1[c];
        x1g[(size_t)i * 10 + c] = v;
        pd = v * Ws[c];
    }
#pragma unroll
    for (int d = 1; d < 16; d <<= 1) pd += __shfl_xor(pd, d, 64);
    if (c == 0) hsg[i] = pd;
}

// ---------------------------------------------------------------------------
// 3. Scorer GCN gather: 4 threads per node, shfl reduce. Zero barriers.
// ---------------------------------------------------------------------------
__global__ __launch_bounds__(256) void k_score(const float* __restrict__ hsg, const float* __restrict__ dinvg,
                                               const int* __restrict__ rowptrg, const unsigned short* __restrict__ csrg,
                                               const float* __restrict__ bs, float* __restrict__ scoreg) {
    int t = blockIdx.x * blockDim.x + threadIdx.x;   // < NTOT*4
    int i = t >> 2, j = t & 3;
    int nbase = i & ~(NPG - 1);
    int p0 = rowptrg[i], p1 = rowptrg[i + 1];
    float a = 0.f;
    for (int e = p0 + j; e < p1; e += 4) {
        int s = nbase + csrg[e];
        a += dinvg[s] * hsg[s];
    }
#pragma unroll
    for (int d = 1; d < 4; d <<= 1) a += __shfl_xor(a, d, 64);
    if (j == 0) {
        float di = dinvg[i];
        scoreg[i] = di * a + hsg[i] * di * di + bs[0];
    }
}

// ---------------------------------------------------------------------------
// 4. Per-graph top-K: 3-level (11/11/10-bit) radix select, wave-shuffle
//    suffix sums, 256 threads (4 waves), ~16 barriers.
// ---------------------------------------------------------------------------
__global__ __launch_bounds__(256) void k_topk(const float* __restrict__ scoreg, int* __restrict__ permg,
                                              int* __restrict__ newidxg) {
    __shared__ unsigned sk[NPG];
    __shared__ int newL[NPG];
    __shared__ int bins[NPG];
    __shared__ int wsum[4];
    __shared__ int bselS, bneedS, curS, totS;
    int g = blockIdx.x, tid = threadIdx.x;
    int nbase = g * NPG;
    int wid = tid >> 6;

    for (int i = tid; i < NPG; i += 256) {
        unsigned u = __float_as_uint(scoreg[nbase + i]);
        sk[i] = (u & 0x80000000u) ? ~u : (u | 0x80000000u);
        newL[i] = -1;
        bins[i] = 0;
    }
    if (tid == 0) curS = 0;
    int need = KSEL;
    unsigned prefix = 0;
    __syncthreads();

    for (int lv = 0; lv < 3; lv++) {
        for (int i = tid; i < NPG; i += 256) {
            unsigned k = sk[i];
            bool match; unsigned bb;
            if (lv == 0)      { match = true;                       bb = k >> 21; }
            else if (lv == 1) { match = ((k >> 21) == prefix);      bb = (k >> 10) & 0x7FFu; }
            else              { match = ((k >> 10) == prefix);      bb = k & 0x3FFu; }
            if (match) atomicAdd(&bins[bb], 1);
        }
        __syncthreads();
        int b8 = tid * 8;
        int v[8], loc[8], s = 0;
#pragma unroll
        for (int k = 0; k < 8; k++) { v[k] = bins[b8 + k]; bins[b8 + k] = 0; loc[k] = s; s += v[k]; }
        int incl = wave_incl_scan(s);
        if ((tid & 63) == 63) wsum[wid] = incl;
        __syncthreads();
        if (tid == 0) {
            int a = 0;
#pragma unroll
            for (int w = 0; w < 4; w++) { int t = wsum[w]; wsum[w] = a; a += t; }
            totS = a;
        }
        __syncthreads();
        int base = wsum[wid] + incl - s;
        int tot = totS;
#pragma unroll
        for (int k = 0; k < 8; k++) {
            int Sb = tot - (base + loc[k]);       // keys in buckets >= b
            int Sb1 = Sb - v[k];                  // buckets > b
            if (Sb >= need && Sb1 < need) { bselS = b8 + k; bneedS = need - Sb1; }
        }
        __syncthreads();
        if (lv == 0)      prefix = (unsigned)bselS;
        else if (lv == 1) prefix = (prefix << 11) | (unsigned)bselS;
        else              prefix = (prefix << 10) | (unsigned)bselS;
        need = bneedS;
        __syncthreads();
    }
    unsigned T = prefix;            // exact K-th largest key; need = #ties to take

    for (int i = tid; i < NPG; i += 256) {
        if (sk[i] > T) {
            int p = g * KSEL + atomicAdd(&curS, 1);
            permg[p] = nbase + i;
            newL[i] = p;
        }
    }
    int b8 = tid * 8;
    int lc = 0, loc[8];
#pragma unroll
    for (int k = 0; k < 8; k++)
        if (sk[b8 + k] == T) loc[lc++] = b8 + k;
    __syncthreads();
    int incl = wave_incl_scan(lc);
    if ((tid & 63) == 63) wsum[wid] = incl;
    __syncthreads();
    if (tid == 0) {
        int a = 0;
#pragma unroll
        for (int w = 0; w < 4; w++) { int t = wsum[w]; wsum[w] = a; a += t; }
    }
    __syncthreads();
    int rank0 = wsum[wid] + incl - lc;
    int greaterCnt = KSEL - need;
    for (int j = 0; j < lc; j++) {
        int rank = rank0 + j;
        if (rank < need) {
            int p = g * KSEL + greaterCnt + rank;
            permg[p] = nbase + loc[j];
            newL[loc[j]] = p;
        }
    }
    __syncthreads();
    for (int i = tid; i < NPG; i += 256) newidxg[nbase + i] = newL[i];
}

// ---------------------------------------------------------------------------
// 5. GAT per (graph, head): features + two-pass softmax agg + butterfly
//    readout. 192 blocks x 512 thr, ~44 KB LDS, ~4 barriers, no atomics.
// ---------------------------------------------------------------------------
__global__ __launch_bounds__(512) void k_gat(
    const float* __restrict__ x1g, const float* __restrict__ scoreg,
    const int* __restrict__ permg, const int* __restrict__ newidxg,
    const int* __restrict__ rowptrg, const unsigned short* __restrict__ csrg,
    const float* __restrict__ Wg, const float* __restrict__ a_srcw,
    const float* __restrict__ a_dstw, const float* __restrict__ bg,
    float* __restrict__ goutg)
{
    __shared__ float hfeatH[KSEL * NC];   // 32.8 KB
    __shared__ float alsH[KSEL];
    __shared__ float aldH[KSEL];
    __shared__ short newLs[NPG];          // 4 KB
    __shared__ int rpL[KSEL];
    __shared__ int rcL[KSEL];
    __shared__ float wgs[10 * NC];
    __shared__ float asr[NC], adr[NC];
    __shared__ float wred[8 * NC];

    int b = blockIdx.x, tid = threadIdx.x;
    int g = b / NH, hh = b - g * NH;
    int nbase = g * NPG, gK = g * KSEL;

    for (int i = tid; i < NPG; i += 512) {
        int v = newidxg[nbase + i];
        newLs[i] = (short)(v >= 0 ? v - gK : -1);
    }
    for (int t = tid; t < 10 * NC; t += 512) {
        int k = t / NC, c = t - k * NC;
        wgs[t] = Wg[k * HC + hh * NC + c];
    }
    if (tid < NC) { asr[tid] = a_srcw[hh * NC + tid]; adr[tid] = a_dstw[hh * NC + tid]; }
    __syncthreads();
    for (int p = tid; p < KSEL; p += 512) {
        int gid = permg[gK + p];
        int rp = rowptrg[gid];
        rpL[p] = rp;
        rcL[p] = rowptrg[gid + 1] - rp;
        float tt = tanhf(scoreg[gid]);
        float xi[10];
#pragma unroll
        for (int k = 0; k < 10; k++) xi[k] = x1g[(size_t)gid * 10 + k] * tt;
        float as_ = 0.f, ad_ = 0.f;
#pragma unroll
        for (int c = 0; c < NC; c++) {
            float v = 0.f;
#pragma unroll
            for (int k = 0; k < 10; k++) v += xi[k] * wgs[k * NC + c];
            hfeatH[p * NC + c] = v;
            as_ += v * asr[c];
            ad_ += v * adr[c];
        }
        alsH[p] = as_;
        aldH[p] = ad_;
    }
    __syncthreads();
    float res[NC];
    if (tid < KSEL) {
        int p = tid;
        float aldp = aldH[p];
        float lself = leaky(alsH[p] + aldp);
        float m = lself;
        int rp = rpL[p], rc = rcL[p];
        for (int e = 0; e < rc; e++) {
            int s2 = newLs[csrg[rp + e]];
            if (s2 >= 0) m = fmaxf(m, leaky(alsH[s2] + aldp));
        }
        float wself = expf(lself - m);
        float wsum = wself;
#pragma unroll
        for (int c = 0; c < NC; c++) res[c] = wself * hfeatH[p * NC + c];
        for (int e = 0; e < rc; e++) {
            int s2 = newLs[csrg[rp + e]];
            if (s2 < 0) continue;
            float w = expf(leaky(alsH[s2] + aldp) - m);
            wsum += w;
            const float* hsrc = hfeatH + s2 * NC;
#pragma unroll
            for (int c = 0; c < NC; c++) res[c] += w * hsrc[c];
        }
        float inv = 1.f / wsum;
#pragma unroll
        for (int c = 0; c < NC; c++) res[c] *= inv;
    } else {
#pragma unroll
        for (int c = 0; c < NC; c++) res[c] = 0.f;
    }
#pragma unroll
    for (int c = 0; c < NC; c++) {
        float v = res[c];
#pragma unroll
        for (int d = 1; d < 64; d <<= 1) v += __shfl_xor(v, d, 64);
        res[c] = v;
    }
    if ((tid & 63) == 0)
#pragma unroll
        for (int c = 0; c < NC; c++) wred[(tid >> 6) * NC + c] = res[c];
    __syncthreads();
    if (tid < NC) {
        float a = 0.f;
#pragma unroll
        for (int w = 0; w < 8; w++) a += wred[w * NC + tid];
        goutg[g * HC + hh * NC + tid] = a + (float)KSEL * bg[hh * NC + tid];
    }
}

// ---------------------------------------------------------------------------
// 6. final MLP + log_softmax
// ---------------------------------------------------------------------------
__global__ __launch_bounds__(64) void k_mlp(const float* __restrict__ gout, const float* __restrict__ Wf1,
                                            const float* __restrict__ bf1, const float* __restrict__ Wf2,
                                            const float* __restrict__ bf2, float* __restrict__ out) {
    int g = threadIdx.x;
    if (g >= G) return;
    float gi[HC];
#pragma unroll
    for (int k = 0; k < HC; k++) gi[k] = gout[g * HC + k];
    float hid[30];
    for (int j = 0; j < 30; j++) {
        float s = bf1[j];
        for (int k = 0; k < HC; k++) s += gi[k] * Wf1[k * 30 + j];
        hid[j] = s > 0.f ? s : 0.f;
    }
    float z[3];
    for (int j = 0; j < 3; j++) {
        float s = bf2[j];
        for (int k = 0; k < 30; k++) s += hid[k] * Wf2[k * 3 + j];
        z[j] = s;
    }
    float m = fmaxf(z[0], fmaxf(z[1], z[2]));
    float lse = logf(expf(z[0] - m) + expf(z[1] - m) + expf(z[2] - m)) + m;
    for (int j = 0; j < 3; j++) out[g * 3 + j] = z[j] - lse;
}

extern "C" void kernel_launch(void* const* d_in, const int* in_sizes, int n_in,
                              void* d_out, int out_size, void* d_ws, size_t ws_size,
                              hipStream_t stream) {
    const float* x     = (const float*)d_in[0];
    const int*   src   = (const int*)d_in[1];
    const int*   dst   = (const int*)d_in[2];
    const float* W1    = (const float*)d_in[4];
    const float* b1    = (const float*)d_in[5];
    const float* Ws    = (const float*)d_in[6];
    const float* bs    = (const float*)d_in[7];
    const float* Wg    = (const float*)d_in[8];
    const float* a_src = (const float*)d_in[9];
    const float* a_dst = (const float*)d_in[10];
    const float* bg    = (const float*)d_in[11];
    const float* Wf1   = (const float*)d_in[12];
    const float* bf1   = (const float*)d_in[13];
    const float* Wf2   = (const float*)d_in[14];
    const float* bf2   = (const float*)d_in[15];
    float* out = (float*)d_out;

    const size_t N = NTOT;
    float* ws = (float*)d_ws;
    float* h1g    = ws;                          // 10N
    float* x1g    = h1g + 10 * N;                // 10N
    float* hsg    = x1g + 10 * N;                // N
    float* dinvg  = hsg + N;                     // N
    float* scoreg = dinvg + N;                   // N
    int* rowptrg  = (int*)(scoreg + N);          // N+1
    int* newidxg  = rowptrg + N + 1;             // N
    int* permg    = newidxg + N;                 // NK
    float* goutg  = (float*)(permg + NK);        // G*HC
    unsigned short* csrg = (unsigned short*)(goutg + G * HC);  // NE ushort

    k_csr<<<G, 1024, 0, stream>>>(x, src, dst, W1, h1g, dinvg, rowptrg, csrg);
    k_gcn10<<<(NTOT * 16) / 256, 256, 0, stream>>>(h1g, dinvg, rowptrg, csrg, b1, Ws, x1g, hsg);
    k_score<<<(NTOT * 4) / 256, 256, 0, stream>>>(hsg, dinvg, rowptrg, csrg, bs, scoreg);
    k_topk<<<G, 256, 0, stream>>>(scoreg, permg, newidxg);
    k_gat<<<G * NH, 512, 0, stream>>>(x1g, scoreg, permg, newidxg, rowptrg, csrg,
                                      Wg, a_src, a_dst, bg, goutg);
    k_mlp<<<1, 64, 0, stream>>>(goutg, Wf1, bf1, Wf2, bf2, out);
}

// Round 8
// 187.693 us; speedup vs baseline: 1.0051x; 1.0051x over previous
//
#include <hip/hip_runtime.h>
#include <math.h>

#define G    64
#define NPG  2048
#define NTOT (G * NPG)          // 131072
#define EPG  (NPG * 8)          // 16384 edges per graph (contiguous by construction)
#define NE   (NTOT * 8)         // 1048576
#define KSEL 410
#define NK   (G * KSEL)         // 26240
#define NH   3
#define NC   20
#define HC   60
#define H1P  16                 // padded h1 row (64 B -> aligned float4 loads)

__device__ inline float leaky(float x) { return x >= 0.f ? x : 0.2f * x; }

__device__ inline int wave_incl_scan(int v) {
    int lane = threadIdx.x & 63;
#pragma unroll
    for (int d = 1; d < 64; d <<= 1) {
        int t = __shfl_up(v, d, 64);
        if (lane >= d) v += t;
    }
    return v;
}

// ---------------------------------------------------------------------------
// 1. Per-graph CSR build (LDS hist -> wave-shuffle scan -> scatter), fused h1
//    (padded rows). 1024 threads, ~48 KB LDS, 5 barriers.
// ---------------------------------------------------------------------------
__global__ __launch_bounds__(1024) void k_csr(
    const float* __restrict__ x, const int* __restrict__ src, const int* __restrict__ dst,
    const float* __restrict__ W1, float* __restrict__ h1g, float* __restrict__ dinvg,
    int* __restrict__ rowptrg, unsigned short* __restrict__ csrg)
{
    __shared__ int hist[NPG];
    __shared__ int rs[NPG];
    __shared__ unsigned short csr[EPG];
    __shared__ int wsum[16];
    int g = blockIdx.x, tid = threadIdx.x;
    int nbase = g * NPG, ebase = g * EPG;

    for (int i = tid; i < NPG; i += 1024) hist[i] = 0;
    for (int i = tid; i < NPG; i += 1024) {
        float xi[5];
#pragma unroll
        for (int k = 0; k < 5; k++) xi[k] = x[(size_t)(nbase + i) * 5 + k];
#pragma unroll
        for (int j = 0; j < 10; j++) {
            float s = 0.f;
#pragma unroll
            for (int k = 0; k < 5; k++) s += xi[k] * W1[k * 10 + j];
            h1g[(size_t)(nbase + i) * H1P + j] = s;
        }
    }
    __syncthreads();
    for (int e = tid; e < EPG; e += 1024)
        atomicAdd(&hist[dst[ebase + e] - nbase], 1);
    __syncthreads();
    int b2 = tid * 2;
    int v0 = hist[b2], v1 = hist[b2 + 1];
    int s = v0 + v1;
    int incl = wave_incl_scan(s);
    int wid = tid >> 6;
    if ((tid & 63) == 63) wsum[wid] = incl;
    __syncthreads();
    if (tid == 0) {
        int a = 0;
#pragma unroll
        for (int w = 0; w < 16; w++) { int t = wsum[w]; wsum[w] = a; a += t; }
    }
    __syncthreads();
    int base = wsum[wid] + incl - s;
    {
        int E0 = base, E1 = base + v0;
        rs[b2] = E0;       rs[b2 + 1] = E1;
        rowptrg[nbase + b2] = ebase + E0;
        rowptrg[nbase + b2 + 1] = ebase + E1;
        dinvg[nbase + b2] = rsqrtf((float)v0 + 1.0f);
        dinvg[nbase + b2 + 1] = rsqrtf((float)v1 + 1.0f);
        hist[b2] = 0; hist[b2 + 1] = 0;
    }
    if (g == G - 1 && tid == 0) rowptrg[NTOT] = NE;
    __syncthreads();
    for (int e = tid; e < EPG; e += 1024) {
        int ee = ebase + e;
        int sl = src[ee] - nbase;
        int dl = dst[ee] - nbase;
        int pos = rs[dl] + atomicAdd(&hist[dl], 1);
        csr[pos] = (unsigned short)sl;
    }
    __syncthreads();
    {
        const unsigned* s4 = (const unsigned*)csr;
        unsigned* d4 = (unsigned*)(csrg + ebase);
        for (int w = tid; w < EPG / 2; w += 1024) d4[w] = s4[w];
    }
}

// ---------------------------------------------------------------------------
// 2. GCN10 gather: 1 thread/node, padded-h1 float4 loads (3 vec loads/edge).
// ---------------------------------------------------------------------------
__global__ __launch_bounds__(256) void k_gcn10(const float* __restrict__ h1, const float* __restrict__ dinvg,
                                               const int* __restrict__ rowptrg, const unsigned short* __restrict__ csrg,
                                               const float* __restrict__ b1, const float* __restrict__ Ws,
                                               float* __restrict__ x1g, float* __restrict__ hsg) {
    int i = blockIdx.x * blockDim.x + threadIdx.x;
    if (i >= NTOT) return;
    int nbase = i & ~(NPG - 1);
    float di = dinvg[i];
    int p0 = rowptrg[i], p1 = rowptrg[i + 1];
    float a0 = 0.f, a1 = 0.f, a2 = 0.f, a3 = 0.f, a4 = 0.f;
    float a5 = 0.f, a6 = 0.f, a7 = 0.f, a8 = 0.f, a9 = 0.f;
    for (int e = p0; e < p1; e++) {
        int s = nbase + csrg[e];
        float dv = dinvg[s];
        const float4* hv = (const float4*)(h1 + (size_t)s * H1P);
        float4 b0 = hv[0], bb1 = hv[1];
        float2 b2 = ((const float2*)hv)[4];
        a0 += b0.x * dv; a1 += b0.y * dv; a2 += b0.z * dv; a3 += b0.w * dv;
        a4 += bb1.x * dv; a5 += bb1.y * dv; a6 += bb1.z * dv; a7 += bb1.w * dv;
        a8 += b2.x * dv; a9 += b2.y * dv;
    }
    const float4* sv = (const float4*)(h1 + (size_t)i * H1P);
    float4 s0 = sv[0], s1 = sv[1];
    float2 s2 = ((const float2*)sv)[4];
    float d2 = di * di;
    float v[10];
    v[0] = a0 * di + s0.x * d2 + b1[0];
    v[1] = a1 * di + s0.y * d2 + b1[1];
    v[2] = a2 * di + s0.z * d2 + b1[2];
    v[3] = a3 * di + s0.w * d2 + b1[3];
    v[4] = a4 * di + s1.x * d2 + b1[4];
    v[5] = a5 * di + s1.y * d2 + b1[5];
    v[6] = a6 * di + s1.z * d2 + b1[6];
    v[7] = a7 * di + s1.w * d2 + b1[7];
    v[8] = a8 * di + s2.x * d2 + b1[8];
    v[9] = a9 * di + s2.y * d2 + b1[9];
    float dot = 0.f;
#pragma unroll
    for (int j = 0; j < 10; j++) {
        x1g[(size_t)i * 10 + j] = v[j];
        dot += v[j] * Ws[j];
    }
    hsg[i] = dot;
}

// ---------------------------------------------------------------------------
// 3. Fused scorer + top-K per graph: stage hs/dinv in LDS, gather score from
//    LDS, 3-level radix select. 256 threads, ~40 KB LDS.
// ---------------------------------------------------------------------------
__global__ __launch_bounds__(256) void k_scoretopk(const float* __restrict__ hsg, const float* __restrict__ dinvg,
                                                   const int* __restrict__ rowptrg, const unsigned short* __restrict__ csrg,
                                                   const float* __restrict__ bs, float* __restrict__ scoreg,
                                                   int* __restrict__ permg, int* __restrict__ newidxg) {
    __shared__ float hsf[NPG];
    __shared__ float dinvs[NPG];
    __shared__ unsigned sk[NPG];
    __shared__ int newL[NPG];
    __shared__ int bins[NPG];
    __shared__ int wsum[4];
    __shared__ int bselS, bneedS, curS, totS;
    int g = blockIdx.x, tid = threadIdx.x;
    int nbase = g * NPG;
    int wid = tid >> 6;

    for (int i = tid; i < NPG; i += 256) {
        hsf[i] = hsg[nbase + i];
        dinvs[i] = dinvg[nbase + i];
        newL[i] = -1;
        bins[i] = 0;
    }
    if (tid == 0) curS = 0;
    __syncthreads();
    float bsv = bs[0];
    for (int i = tid; i < NPG; i += 256) {
        float di = dinvs[i];
        int p0 = rowptrg[nbase + i], p1 = rowptrg[nbase + i + 1];
        float a = 0.f;
        for (int e = p0; e < p1; e++) {
            int s = csrg[e];
            a += dinvs[s] * hsf[s];
        }
        float sc = di * a + hsf[i] * di * di + bsv;
        scoreg[nbase + i] = sc;
        unsigned u = __float_as_uint(sc);
        sk[i] = (u & 0x80000000u) ? ~u : (u | 0x80000000u);
    }
    int need = KSEL;
    unsigned prefix = 0;
    __syncthreads();

    for (int lv = 0; lv < 3; lv++) {
        for (int i = tid; i < NPG; i += 256) {
            unsigned k = sk[i];
            bool match; unsigned bb;
            if (lv == 0)      { match = true;                       bb = k >> 21; }
            else if (lv == 1) { match = ((k >> 21) == prefix);      bb = (k >> 10) & 0x7FFu; }
            else              { match = ((k >> 10) == prefix);      bb = k & 0x3FFu; }
            if (match) atomicAdd(&bins[bb], 1);
        }
        __syncthreads();
        int b8 = tid * 8;
        int v[8], loc[8], s = 0;
#pragma unroll
        for (int k = 0; k < 8; k++) { v[k] = bins[b8 + k]; bins[b8 + k] = 0; loc[k] = s; s += v[k]; }
        int incl = wave_incl_scan(s);
        if ((tid & 63) == 63) wsum[wid] = incl;
        __syncthreads();
        if (tid == 0) {
            int a = 0;
#pragma unroll
            for (int w = 0; w < 4; w++) { int t = wsum[w]; wsum[w] = a; a += t; }
            totS = a;
        }
        __syncthreads();
        int base = wsum[wid] + incl - s;
        int tot = totS;
#pragma unroll
        for (int k = 0; k < 8; k++) {
            int Sb = tot - (base + loc[k]);
            int Sb1 = Sb - v[k];
            if (Sb >= need && Sb1 < need) { bselS = b8 + k; bneedS = need - Sb1; }
        }
        __syncthreads();
        if (lv == 0)      prefix = (unsigned)bselS;
        else if (lv == 1) prefix = (prefix << 11) | (unsigned)bselS;
        else              prefix = (prefix << 10) | (unsigned)bselS;
        need = bneedS;
        __syncthreads();
    }
    unsigned T = prefix;

    for (int i = tid; i < NPG; i += 256) {
        if (sk[i] > T) {
            int p = g * KSEL + atomicAdd(&curS, 1);
            permg[p] = nbase + i;
            newL[i] = p;
        }
    }
    int b8 = tid * 8;
    int lc = 0, loc[8];
#pragma unroll
    for (int k = 0; k < 8; k++)
        if (sk[b8 + k] == T) loc[lc++] = b8 + k;
    __syncthreads();
    int incl = wave_incl_scan(lc);
    if ((tid & 63) == 63) wsum[wid] = incl;
    __syncthreads();
    if (tid == 0) {
        int a = 0;
#pragma unroll
        for (int w = 0; w < 4; w++) { int t = wsum[w]; wsum[w] = a; a += t; }
    }
    __syncthreads();
    int rank0 = wsum[wid] + incl - lc;
    int greaterCnt = KSEL - need;
    for (int j = 0; j < lc; j++) {
        int rank = rank0 + j;
        if (rank < need) {
            int p = g * KSEL + greaterCnt + rank;
            permg[p] = nbase + loc[j];
            newL[loc[j]] = p;
        }
    }
    __syncthreads();
    for (int i = tid; i < NPG; i += 256) newidxg[nbase + i] = newL[i];
}

// ---------------------------------------------------------------------------
// 4. GAT per (graph, head): float4 LDS traffic; two-pass softmax; butterfly
//    readout. 192 blocks x 512 thr, ~45 KB LDS.
// ---------------------------------------------------------------------------
__global__ __launch_bounds__(512) void k_gat(
    const float* __restrict__ x1g, const float* __restrict__ scoreg,
    const int* __restrict__ permg, const int* __restrict__ newidxg,
    const int* __restrict__ rowptrg, const unsigned short* __restrict__ csrg,
    const float* __restrict__ Wg, const float* __restrict__ a_srcw,
    const float* __restrict__ a_dstw, const float* __restrict__ bg,
    float* __restrict__ goutg)
{
    __shared__ float4 hf4[KSEL * 5];      // 32.8 KB, feature rows as 5 x float4
    __shared__ float alsH[KSEL];
    __shared__ float aldH[KSEL];
    __shared__ short newLs[NPG];          // 4 KB
    __shared__ int rpL[KSEL];
    __shared__ int rcL[KSEL];
    __shared__ float wgs[10 * NC];
    __shared__ float asr[NC], adr[NC];
    __shared__ float wred[8 * NC];

    int b = blockIdx.x, tid = threadIdx.x;
    int g = b / NH, hh = b - g * NH;
    int nbase = g * NPG, gK = g * KSEL;

    for (int i = tid; i < NPG; i += 512) {
        int v = newidxg[nbase + i];
        newLs[i] = (short)(v >= 0 ? v - gK : -1);
    }
    for (int t = tid; t < 10 * NC; t += 512) {
        int k = t / NC, c = t - k * NC;
        wgs[t] = Wg[k * HC + hh * NC + c];
    }
    if (tid < NC) { asr[tid] = a_srcw[hh * NC + tid]; adr[tid] = a_dstw[hh * NC + tid]; }
    __syncthreads();
    for (int p = tid; p < KSEL; p += 512) {
        int gid = permg[gK + p];
        int rp = rowptrg[gid];
        rpL[p] = rp;
        rcL[p] = rowptrg[gid + 1] - rp;
        float tt = tanhf(scoreg[gid]);
        float xi[10];
#pragma unroll
        for (int k = 0; k < 10; k++) xi[k] = x1g[(size_t)gid * 10 + k] * tt;
        float v[NC];
        float as_ = 0.f, ad_ = 0.f;
#pragma unroll
        for (int c = 0; c < NC; c++) {
            float vv = 0.f;
#pragma unroll
            for (int k = 0; k < 10; k++) vv += xi[k] * wgs[k * NC + c];
            v[c] = vv;
            as_ += vv * asr[c];
            ad_ += vv * adr[c];
        }
#pragma unroll
        for (int q = 0; q < 5; q++)
            hf4[p * 5 + q] = make_float4(v[4 * q], v[4 * q + 1], v[4 * q + 2], v[4 * q + 3]);
        alsH[p] = as_;
        aldH[p] = ad_;
    }
    __syncthreads();
    float res[NC];
    if (tid < KSEL) {
        int p = tid;
        float aldp = aldH[p];
        float lself = leaky(alsH[p] + aldp);
        float m = lself;
        int rp = rpL[p], rc = rcL[p];
        for (int e = 0; e < rc; e++) {
            int s2 = newLs[csrg[rp + e]];
            if (s2 >= 0) m = fmaxf(m, leaky(alsH[s2] + aldp));
        }
        float wself = expf(lself - m);
        float wsum = wself;
        float4 r[5];
#pragma unroll
        for (int q = 0; q < 5; q++) {
            float4 t = hf4[p * 5 + q];
            r[q] = make_float4(wself * t.x, wself * t.y, wself * t.z, wself * t.w);
        }
        for (int e = 0; e < rc; e++) {
            int s2 = newLs[csrg[rp + e]];
            if (s2 < 0) continue;
            float w = expf(leaky(alsH[s2] + aldp) - m);
            wsum += w;
#pragma unroll
            for (int q = 0; q < 5; q++) {
                float4 t = hf4[s2 * 5 + q];
                r[q].x += w * t.x; r[q].y += w * t.y; r[q].z += w * t.z; r[q].w += w * t.w;
            }
        }
        float inv = 1.f / wsum;
#pragma unroll
        for (int q = 0; q < 5; q++) {
            res[4 * q]     = r[q].x * inv;
            res[4 * q + 1] = r[q].y * inv;
            res[4 * q + 2] = r[q].z * inv;
            res[4 * q + 3] = r[q].w * inv;
        }
    } else {
#pragma unroll
        for (int c = 0; c < NC; c++) res[c] = 0.f;
    }
#pragma unroll
    for (int c = 0; c < NC; c++) {
        float v = res[c];
#pragma unroll
        for (int d = 1; d < 64; d <<= 1) v += __shfl_xor(v, d, 64);
        res[c] = v;
    }
    if ((tid & 63) == 0)
#pragma unroll
        for (int c = 0; c < NC; c++) wred[(tid >> 6) * NC + c] = res[c];
    __syncthreads();
    if (tid < NC) {
        float a = 0.f;
#pragma unroll
        for (int w = 0; w < 8; w++) a += wred[w * NC + tid];
        goutg[g * HC + hh * NC + tid] = a + (float)KSEL * bg[hh * NC + tid];
    }
}

// ---------------------------------------------------------------------------
// 5. final MLP + log_softmax
// ---------------------------------------------------------------------------
__global__ __launch_bounds__(64) void k_mlp(const float* __restrict__ gout, const float* __restrict__ Wf1,
                                            const float* __restrict__ bf1, const float* __restrict__ Wf2,
                                            const float* __restrict__ bf2, float* __restrict__ out) {
    int g = threadIdx.x;
    if (g >= G) return;
    float gi[HC];
#pragma unroll
    for (int k = 0; k < HC; k++) gi[k] = gout[g * HC + k];
    float hid[30];
    for (int j = 0; j < 30; j++) {
        float s = bf1[j];
        for (int k = 0; k < HC; k++) s += gi[k] * Wf1[k * 30 + j];
        hid[j] = s > 0.f ? s : 0.f;
    }
    float z[3];
    for (int j = 0; j < 3; j++) {
        float s = bf2[j];
        for (int k = 0; k < 30; k++) s += hid[k] * Wf2[k * 3 + j];
        z[j] = s;
    }
    float m = fmaxf(z[0], fmaxf(z[1], z[2]));
    float lse = logf(expf(z[0] - m) + expf(z[1] - m) + expf(z[2] - m)) + m;
    for (int j = 0; j < 3; j++) out[g * 3 + j] = z[j] - lse;
}

extern "C" void kernel_launch(void* const* d_in, const int* in_sizes, int n_in,
                              void* d_out, int out_size, void* d_ws, size_t ws_size,
                              hipStream_t stream) {
    const float* x     = (const float*)d_in[0];
    const int*   src   = (const int*)d_in[1];
    const int*   dst   = (const int*)d_in[2];
    const float* W1    = (const float*)d_in[4];
    const float* b1    = (const float*)d_in[5];
    const float* Ws    = (const float*)d_in[6];
    const float* bs    = (const float*)d_in[7];
    const float* Wg    = (const float*)d_in[8];
    const float* a_src = (const float*)d_in[9];
    const float* a_dst = (const float*)d_in[10];
    const float* bg    = (const float*)d_in[11];
    const float* Wf1   = (const float*)d_in[12];
    const float* bf1   = (const float*)d_in[13];
    const float* Wf2   = (const float*)d_in[14];
    const float* bf2   = (const float*)d_in[15];
    float* out = (float*)d_out;

    const size_t N = NTOT;
    float* ws = (float*)d_ws;
    float* h1g    = ws;                          // 16N (padded rows)
    float* x1g    = h1g + (size_t)H1P * N;       // 10N
    float* hsg    = x1g + 10 * N;                // N
    float* dinvg  = hsg + N;                     // N
    float* scoreg = dinvg + N;                   // N
    int* rowptrg  = (int*)(scoreg + N);          // N+1
    int* newidxg  = rowptrg + N + 1;             // N
    int* permg    = newidxg + N;                 // NK
    float* goutg  = (float*)(permg + NK);        // G*HC
    unsigned short* csrg = (unsigned short*)(goutg + G * HC);  // NE ushort

    k_csr<<<G, 1024, 0, stream>>>(x, src, dst, W1, h1g, dinvg, rowptrg, csrg);
    k_gcn10<<<NTOT / 256, 256, 0, stream>>>(h1g, dinvg, rowptrg, csrg, b1, Ws, x1g, hsg);
    k_scoretopk<<<G, 256, 0, stream>>>(hsg, dinvg, rowptrg, csrg, bs, scoreg, permg, newidxg);
    k_gat<<<G * NH, 512, 0, stream>>>(x1g, scoreg, permg, newidxg, rowptrg, csrg,
                                      Wg, a_src, a_dst, bg, goutg);
    k_mlp<<<1, 64, 0, stream>>>(goutg, Wf1, bf1, Wf2, bf2, out);
}

// Round 9
// 169.474 us; speedup vs baseline: 1.1132x; 1.1075x over previous
//
#include <hip/hip_runtime.h>
#include <math.h>

#define G    64
#define NPG  2048
#define NTOT (G * NPG)          // 131072
#define EPG  (NPG * 8)          // 16384 edges per graph (contiguous by construction)
#define NE   (NTOT * 8)         // 1048576
#define KSEL 410
#define NK   (G * KSEL)         // 26240
#define NH   3
#define NC   20
#define HC   60
#define H1P  16                 // padded h1 row (64 B -> aligned float4 loads)
#define FCAP 24                 // max surviving in-edges per pooled node

__device__ inline float leaky(float x) { return x >= 0.f ? x : 0.2f * x; }

__device__ inline int wave_incl_scan(int v) {
    int lane = threadIdx.x & 63;
#pragma unroll
    for (int d = 1; d < 64; d <<= 1) {
        int t = __shfl_up(v, d, 64);
        if (lane >= d) v += t;
    }
    return v;
}

// ---------------------------------------------------------------------------
// 1. Per-graph CSR build (LDS hist -> wave-shuffle scan -> scatter), fused h1
//    (padded rows). 1024 threads, ~48 KB LDS, 5 barriers.
// ---------------------------------------------------------------------------
__global__ __launch_bounds__(1024) void k_csr(
    const float* __restrict__ x, const int* __restrict__ src, const int* __restrict__ dst,
    const float* __restrict__ W1, float* __restrict__ h1g, float* __restrict__ dinvg,
    int* __restrict__ rowptrg, unsigned short* __restrict__ csrg)
{
    __shared__ int hist[NPG];
    __shared__ int rs[NPG];
    __shared__ unsigned short csr[EPG];
    __shared__ int wsum[16];
    int g = blockIdx.x, tid = threadIdx.x;
    int nbase = g * NPG, ebase = g * EPG;

    for (int i = tid; i < NPG; i += 1024) hist[i] = 0;
    for (int i = tid; i < NPG; i += 1024) {
        float xi[5];
#pragma unroll
        for (int k = 0; k < 5; k++) xi[k] = x[(size_t)(nbase + i) * 5 + k];
#pragma unroll
        for (int j = 0; j < 10; j++) {
            float s = 0.f;
#pragma unroll
            for (int k = 0; k < 5; k++) s += xi[k] * W1[k * 10 + j];
            h1g[(size_t)(nbase + i) * H1P + j] = s;
        }
    }
    __syncthreads();
    for (int e = tid; e < EPG; e += 1024)
        atomicAdd(&hist[dst[ebase + e] - nbase], 1);
    __syncthreads();
    int b2 = tid * 2;
    int v0 = hist[b2], v1 = hist[b2 + 1];
    int s = v0 + v1;
    int incl = wave_incl_scan(s);
    int wid = tid >> 6;
    if ((tid & 63) == 63) wsum[wid] = incl;
    __syncthreads();
    if (tid == 0) {
        int a = 0;
#pragma unroll
        for (int w = 0; w < 16; w++) { int t = wsum[w]; wsum[w] = a; a += t; }
    }
    __syncthreads();
    int base = wsum[wid] + incl - s;
    {
        int E0 = base, E1 = base + v0;
        rs[b2] = E0;       rs[b2 + 1] = E1;
        rowptrg[nbase + b2] = ebase + E0;
        rowptrg[nbase + b2 + 1] = ebase + E1;
        dinvg[nbase + b2] = rsqrtf((float)v0 + 1.0f);
        dinvg[nbase + b2 + 1] = rsqrtf((float)v1 + 1.0f);
        hist[b2] = 0; hist[b2 + 1] = 0;
    }
    if (g == G - 1 && tid == 0) rowptrg[NTOT] = NE;
    __syncthreads();
    for (int e = tid; e < EPG; e += 1024) {
        int ee = ebase + e;
        int sl = src[ee] - nbase;
        int dl = dst[ee] - nbase;
        int pos = rs[dl] + atomicAdd(&hist[dl], 1);
        csr[pos] = (unsigned short)sl;
    }
    __syncthreads();
    {
        const unsigned* s4 = (const unsigned*)csr;
        unsigned* d4 = (unsigned*)(csrg + ebase);
        for (int w = tid; w < EPG / 2; w += 1024) d4[w] = s4[w];
    }
}

// ---------------------------------------------------------------------------
// 2. GCN10 gather: 1 thread/node, padded-h1 float4 loads.
// ---------------------------------------------------------------------------
__global__ __launch_bounds__(256) void k_gcn10(const float* __restrict__ h1, const float* __restrict__ dinvg,
                                               const int* __restrict__ rowptrg, const unsigned short* __restrict__ csrg,
                                               const float* __restrict__ b1, const float* __restrict__ Ws,
                                               float* __restrict__ x1g, float* __restrict__ hsg) {
    int i = blockIdx.x * blockDim.x + threadIdx.x;
    if (i >= NTOT) return;
    int nbase = i & ~(NPG - 1);
    float di = dinvg[i];
    int p0 = rowptrg[i], p1 = rowptrg[i + 1];
    float a0 = 0.f, a1 = 0.f, a2 = 0.f, a3 = 0.f, a4 = 0.f;
    float a5 = 0.f, a6 = 0.f, a7 = 0.f, a8 = 0.f, a9 = 0.f;
    for (int e = p0; e < p1; e++) {
        int s = nbase + csrg[e];
        float dv = dinvg[s];
        const float4* hv = (const float4*)(h1 + (size_t)s * H1P);
        float4 b0 = hv[0], bb1 = hv[1];
        float2 b2 = ((const float2*)hv)[4];
        a0 += b0.x * dv; a1 += b0.y * dv; a2 += b0.z * dv; a3 += b0.w * dv;
        a4 += bb1.x * dv; a5 += bb1.y * dv; a6 += bb1.z * dv; a7 += bb1.w * dv;
        a8 += b2.x * dv; a9 += b2.y * dv;
    }
    const float4* sv = (const float4*)(h1 + (size_t)i * H1P);
    float4 s0 = sv[0], s1 = sv[1];
    float2 s2 = ((const float2*)sv)[4];
    float d2 = di * di;
    float v[10];
    v[0] = a0 * di + s0.x * d2 + b1[0];
    v[1] = a1 * di + s0.y * d2 + b1[1];
    v[2] = a2 * di + s0.z * d2 + b1[2];
    v[3] = a3 * di + s0.w * d2 + b1[3];
    v[4] = a4 * di + s1.x * d2 + b1[4];
    v[5] = a5 * di + s1.y * d2 + b1[5];
    v[6] = a6 * di + s1.z * d2 + b1[6];
    v[7] = a7 * di + s1.w * d2 + b1[7];
    v[8] = a8 * di + s2.x * d2 + b1[8];
    v[9] = a9 * di + s2.y * d2 + b1[9];
    float dot = 0.f;
#pragma unroll
    for (int j = 0; j < 10; j++) {
        x1g[(size_t)i * 10 + j] = v[j];
        dot += v[j] * Ws[j];
    }
    hsg[i] = dot;
}

// ---------------------------------------------------------------------------
// 3. Fused scorer + top-K + filtered-adjacency, per graph. 512 threads,
//    ~83 KB LDS (csr staged). Emits perm, score, fadj/fcnt (pooled adjacency).
// ---------------------------------------------------------------------------
__global__ __launch_bounds__(512) void k_scoretopk(
    const float* __restrict__ hsg, const float* __restrict__ dinvg,
    const int* __restrict__ rowptrg, const unsigned short* __restrict__ csrg,
    const float* __restrict__ bs, float* __restrict__ scoreg,
    int* __restrict__ permg, unsigned short* __restrict__ fadjg, int* __restrict__ fcntg)
{
    __shared__ unsigned short csrL[EPG];   // 32 KB
    __shared__ int rsL[NPG + 1];
    __shared__ float hsf[NPG];
    __shared__ float dinvs[NPG];
    __shared__ unsigned sk[NPG];
    __shared__ int newL[NPG];
    __shared__ int bins[NPG];
    __shared__ unsigned short permL[KSEL];
    __shared__ int wsum[8];
    __shared__ int bselS, bneedS, curS, totS;
    int g = blockIdx.x, tid = threadIdx.x;
    int nbase = g * NPG, ebase = g * EPG;
    int wid = tid >> 6;

    {   // stage csr coalesced
        const unsigned* s4 = (const unsigned*)(csrg + ebase);
        unsigned* d4 = (unsigned*)csrL;
        for (int w = tid; w < EPG / 2; w += 512) d4[w] = s4[w];
    }
    for (int i = tid; i < NPG; i += 512) {
        rsL[i] = rowptrg[nbase + i] - ebase;
        hsf[i] = hsg[nbase + i];
        dinvs[i] = dinvg[nbase + i];
        newL[i] = -1;
        bins[i] = 0;
    }
    if (tid == 0) { rsL[NPG] = EPG; curS = 0; }
    __syncthreads();
    float bsv = bs[0];
    for (int i = tid; i < NPG; i += 512) {
        float di = dinvs[i];
        int p0 = rsL[i], p1 = rsL[i + 1];
        float a = 0.f;
        for (int e = p0; e < p1; e++) {
            int s = csrL[e];
            a += dinvs[s] * hsf[s];
        }
        float sc = di * a + hsf[i] * di * di + bsv;
        scoreg[nbase + i] = sc;
        unsigned u = __float_as_uint(sc);
        sk[i] = (u & 0x80000000u) ? ~u : (u | 0x80000000u);
    }
    int need = KSEL;
    unsigned prefix = 0;
    __syncthreads();

    for (int lv = 0; lv < 3; lv++) {
        for (int i = tid; i < NPG; i += 512) {
            unsigned k = sk[i];
            bool match; unsigned bb;
            if (lv == 0)      { match = true;                       bb = k >> 21; }
            else if (lv == 1) { match = ((k >> 21) == prefix);      bb = (k >> 10) & 0x7FFu; }
            else              { match = ((k >> 10) == prefix);      bb = k & 0x3FFu; }
            if (match) atomicAdd(&bins[bb], 1);
        }
        __syncthreads();
        int b4 = tid * 4;
        int v[4], loc[4], s = 0;
#pragma unroll
        for (int k = 0; k < 4; k++) { v[k] = bins[b4 + k]; bins[b4 + k] = 0; loc[k] = s; s += v[k]; }
        int incl = wave_incl_scan(s);
        if ((tid & 63) == 63) wsum[wid] = incl;
        __syncthreads();
        if (tid == 0) {
            int a = 0;
#pragma unroll
            for (int w = 0; w < 8; w++) { int t = wsum[w]; wsum[w] = a; a += t; }
            totS = a;
        }
        __syncthreads();
        int base = wsum[wid] + incl - s;
        int tot = totS;
#pragma unroll
        for (int k = 0; k < 4; k++) {
            int Sb = tot - (base + loc[k]);       // keys in buckets >= b
            int Sb1 = Sb - v[k];                  // buckets > b
            if (Sb >= need && Sb1 < need) { bselS = b4 + k; bneedS = need - Sb1; }
        }
        __syncthreads();
        if (lv == 0)      prefix = (unsigned)bselS;
        else if (lv == 1) prefix = (prefix << 11) | (unsigned)bselS;
        else              prefix = (prefix << 10) | (unsigned)bselS;
        need = bneedS;
        __syncthreads();
    }
    unsigned T = prefix;            // K-th largest key; need = #ties to take

    for (int i = tid; i < NPG; i += 512) {
        if (sk[i] > T) {
            int p = atomicAdd(&curS, 1);
            permg[g * KSEL + p] = nbase + i;
            permL[p] = (unsigned short)i;
            newL[i] = p;
        }
    }
    int b4 = tid * 4;
    int lc = 0, loc[4];
#pragma unroll
    for (int k = 0; k < 4; k++)
        if (sk[b4 + k] == T) loc[lc++] = b4 + k;
    __syncthreads();
    int incl = wave_incl_scan(lc);
    if ((tid & 63) == 63) wsum[wid] = incl;
    __syncthreads();
    if (tid == 0) {
        int a = 0;
#pragma unroll
        for (int w = 0; w < 8; w++) { int t = wsum[w]; wsum[w] = a; a += t; }
    }
    __syncthreads();
    int rank0 = wsum[wid] + incl - lc;
    int greaterCnt = KSEL - need;
    for (int j = 0; j < lc; j++) {
        int rank = rank0 + j;
        if (rank < need) {
            int p = greaterCnt + rank;
            permg[g * KSEL + p] = nbase + loc[j];
            permL[p] = (unsigned short)loc[j];
            newL[loc[j]] = p;
        }
    }
    __syncthreads();
    // filtered pooled adjacency: survivors only, local pooled ids
    for (int p = tid; p < KSEL; p += 512) {
        int iL = permL[p];
        int p0 = rsL[iL], p1 = rsL[iL + 1];
        int gp = g * KSEL + p;
        unsigned short* f = fadjg + (size_t)gp * FCAP;
        int c = 0;
        for (int e = p0; e < p1; e++) {
            int s2 = newL[csrL[e]];
            if (s2 >= 0 && c < FCAP) f[c++] = (unsigned short)s2;
        }
        fcntg[gp] = c;
    }
}

// ---------------------------------------------------------------------------
// 4. GAT per (graph, head) on the filtered adjacency. 192 x 512, ~38 KB LDS.
// ---------------------------------------------------------------------------
__global__ __launch_bounds__(512) void k_gat(
    const float* __restrict__ x1g, const float* __restrict__ scoreg,
    const int* __restrict__ permg, const unsigned short* __restrict__ fadjg,
    const int* __restrict__ fcntg, const float* __restrict__ Wg,
    const float* __restrict__ a_srcw, const float* __restrict__ a_dstw,
    const float* __restrict__ bg, float* __restrict__ goutg)
{
    __shared__ float4 hf4[KSEL * 5];      // 32.8 KB
    __shared__ float alsH[KSEL];
    __shared__ float aldH[KSEL];
    __shared__ float wgs[10 * NC];
    __shared__ float asr[NC], adr[NC];
    __shared__ float wred[8 * NC];

    int b = blockIdx.x, tid = threadIdx.x;
    int g = b / NH, hh = b - g * NH;
    int gK = g * KSEL;

    for (int t = tid; t < 10 * NC; t += 512) {
        int k = t / NC, c = t - k * NC;
        wgs[t] = Wg[k * HC + hh * NC + c];
    }
    if (tid < NC) { asr[tid] = a_srcw[hh * NC + tid]; adr[tid] = a_dstw[hh * NC + tid]; }
    __syncthreads();
    for (int p = tid; p < KSEL; p += 512) {
        int gid = permg[gK + p];
        float tt = tanhf(scoreg[gid]);
        float xi[10];
#pragma unroll
        for (int k = 0; k < 10; k++) xi[k] = x1g[(size_t)gid * 10 + k] * tt;
        float v[NC];
        float as_ = 0.f, ad_ = 0.f;
#pragma unroll
        for (int c = 0; c < NC; c++) {
            float vv = 0.f;
#pragma unroll
            for (int k = 0; k < 10; k++) vv += xi[k] * wgs[k * NC + c];
            v[c] = vv;
            as_ += vv * asr[c];
            ad_ += vv * adr[c];
        }
#pragma unroll
        for (int q = 0; q < 5; q++)
            hf4[p * 5 + q] = make_float4(v[4 * q], v[4 * q + 1], v[4 * q + 2], v[4 * q + 3]);
        alsH[p] = as_;
        aldH[p] = ad_;
    }
    __syncthreads();
    float res[NC];
    if (tid < KSEL) {
        int p = tid, gp = gK + p;
        float aldp = aldH[p];
        float lself = leaky(alsH[p] + aldp);
        float m = lself;
        int c = fcntg[gp];
        const unsigned short* f = fadjg + (size_t)gp * FCAP;
        for (int e = 0; e < c; e++)
            m = fmaxf(m, leaky(alsH[f[e]] + aldp));
        float wself = expf(lself - m);
        float wsum = wself;
        float4 r[5];
#pragma unroll
        for (int q = 0; q < 5; q++) {
            float4 t = hf4[p * 5 + q];
            r[q] = make_float4(wself * t.x, wself * t.y, wself * t.z, wself * t.w);
        }
        for (int e = 0; e < c; e++) {
            int s2 = f[e];
            float w = expf(leaky(alsH[s2] + aldp) - m);
            wsum += w;
#pragma unroll
            for (int q = 0; q < 5; q++) {
                float4 t = hf4[s2 * 5 + q];
                r[q].x += w * t.x; r[q].y += w * t.y; r[q].z += w * t.z; r[q].w += w * t.w;
            }
        }
        float inv = 1.f / wsum;
#pragma unroll
        for (int q = 0; q < 5; q++) {
            res[4 * q]     = r[q].x * inv;
            res[4 * q + 1] = r[q].y * inv;
            res[4 * q + 2] = r[q].z * inv;
            res[4 * q + 3] = r[q].w * inv;
        }
    } else {
#pragma unroll
        for (int c = 0; c < NC; c++) res[c] = 0.f;
    }
#pragma unroll
    for (int c = 0; c < NC; c++) {
        float v = res[c];
#pragma unroll
        for (int d = 1; d < 64; d <<= 1) v += __shfl_xor(v, d, 64);
        res[c] = v;
    }
    if ((tid & 63) == 0)
#pragma unroll
        for (int c = 0; c < NC; c++) wred[(tid >> 6) * NC + c] = res[c];
    __syncthreads();
    if (tid < NC) {
        float a = 0.f;
#pragma unroll
        for (int w = 0; w < 8; w++) a += wred[w * NC + tid];
        goutg[g * HC + hh * NC + tid] = a + (float)KSEL * bg[hh * NC + tid];
    }
}

// ---------------------------------------------------------------------------
// 5. final MLP + log_softmax
// ---------------------------------------------------------------------------
__global__ __launch_bounds__(64) void k_mlp(const float* __restrict__ gout, const float* __restrict__ Wf1,
                                            const float* __restrict__ bf1, const float* __restrict__ Wf2,
                                            const float* __restrict__ bf2, float* __restrict__ out) {
    int g = threadIdx.x;
    if (g >= G) return;
    float gi[HC];
#pragma unroll
    for (int k = 0; k < HC; k++) gi[k] = gout[g * HC + k];
    float hid[30];
    for (int j = 0; j < 30; j++) {
        float s = bf1[j];
        for (int k = 0; k < HC; k++) s += gi[k] * Wf1[k * 30 + j];
        hid[j] = s > 0.f ? s : 0.f;
    }
    float z[3];
    for (int j = 0; j < 3; j++) {
        float s = bf2[j];
        for (int k = 0; k < 30; k++) s += hid[k] * Wf2[k * 3 + j];
        z[j] = s;
    }
    float m = fmaxf(z[0], fmaxf(z[1], z[2]));
    float lse = logf(expf(z[0] - m) + expf(z[1] - m) + expf(z[2] - m)) + m;
    for (int j = 0; j < 3; j++) out[g * 3 + j] = z[j] - lse;
}

extern "C" void kernel_launch(void* const* d_in, const int* in_sizes, int n_in,
                              void* d_out, int out_size, void* d_ws, size_t ws_size,
                              hipStream_t stream) {
    const float* x     = (const float*)d_in[0];
    const int*   src   = (const int*)d_in[1];
    const int*   dst   = (const int*)d_in[2];
    const float* W1    = (const float*)d_in[4];
    const float* b1    = (const float*)d_in[5];
    const float* Ws    = (const float*)d_in[6];
    const float* bs    = (const float*)d_in[7];
    const float* Wg    = (const float*)d_in[8];
    const float* a_src = (const float*)d_in[9];
    const float* a_dst = (const float*)d_in[10];
    const float* bg    = (const float*)d_in[11];
    const float* Wf1   = (const float*)d_in[12];
    const float* bf1   = (const float*)d_in[13];
    const float* Wf2   = (const float*)d_in[14];
    const float* bf2   = (const float*)d_in[15];
    float* out = (float*)d_out;

    const size_t N = NTOT;
    float* ws = (float*)d_ws;
    float* h1g    = ws;                          // 16N (padded rows)
    float* x1g    = h1g + (size_t)H1P * N;       // 10N
    float* hsg    = x1g + 10 * N;                // N
    float* dinvg  = hsg + N;                     // N
    float* scoreg = dinvg + N;                   // N
    int* rowptrg  = (int*)(scoreg + N);          // N+1
    int* permg    = rowptrg + N + 1;             // NK
    int* fcntg    = permg + NK;                  // NK
    float* goutg  = (float*)(fcntg + NK);        // G*HC
    unsigned short* csrg = (unsigned short*)(goutg + G * HC);  // NE ushort
    unsigned short* fadjg = csrg + NE;           // NK*FCAP ushort

    k_csr<<<G, 1024, 0, stream>>>(x, src, dst, W1, h1g, dinvg, rowptrg, csrg);
    k_gcn10<<<NTOT / 256, 256, 0, stream>>>(h1g, dinvg, rowptrg, csrg, b1, Ws, x1g, hsg);
    k_scoretopk<<<G, 512, 0, stream>>>(hsg, dinvg, rowptrg, csrg, bs, scoreg, permg, fadjg, fcntg);
    k_gat<<<G * NH, 512, 0, stream>>>(x1g, scoreg, permg, fadjg, fcntg,
                                      Wg, a_src, a_dst, bg, goutg);
    k_mlp<<<1, 64, 0, stream>>>(goutg, Wf1, bf1, Wf2, bf2, out);
}

// Round 10
// 154.835 us; speedup vs baseline: 1.2184x; 1.0945x over previous
//
#include <hip/hip_runtime.h>
#include <math.h>

#define G    64
#define NPG  2048
#define NTOT (G * NPG)          // 131072
#define EPG  (NPG * 8)          // 16384 edges per graph (contiguous by construction)
#define NE   (NTOT * 8)         // 1048576
#define KSEL 410
#define NH   3
#define NC   20
#define HC   60
#define FCAP 24
#define KPAD 512

// ---- LDS arena offsets (bytes). Regions are phase-aliased; comments give lifetime.
#define OFF_H1    0             // 81920  h1L 2048x10f          [A..B]
#define OFF_XP    0             // 16400  xpL 410x10f           [E..F]
#define OFF_FADJ  16400         // 19680  fadjL 410x24 u16      [E..G]
#define OFF_SK    36864         // 8192   skL u32               [C..D]
#define OFF_NEWL  45056         // 8192   newL int              [C..E]
#define OFF_SCORE 53248         // 8192   scoreL f              [C..E]
#define OFF_PERML 61440         // 820    permL u16             [D..E]
#define OFF_CSR   81920         // 32768  csrL u16 EPG          [A..E]
#define OFF_HIST  114688        // 8192   hist/bins int         [A..D]
#define OFF_RS    122880        // 8196   rsL int NPG+1         [A..E]
#define OFF_DINV  131080        // 8192   dinvL f               [A..C]
#define OFF_HS    139272        // 8192   hsL f                 [B..C]
#define OFF_HF    36864         // 98400  hfL 410x60f           [F..G] (overwrites SK..HS)
#define OFF_ALS   135264        // 4920   alsL 410x3f           [F..G]
#define OFF_ALD   140184        // 4920   aldL
#define OFF_FCNT  145104        // 1640   fcntL 410 int         [E..G]
#define OFF_WRED  146744        // 1920   wred 24x20f           [G]
#define OFF_GOUT  148664        // 240    goutL 60f             [G..H]
#define OFF_HID   148904        // 120    hidL 30f              [H]
#define OFF_WSUM  149032        // 64     wave partials
#define OFF_FLAGS 149096        // 16     bsel/bneed/cur/tot
#define ARENA_SZ  149112

__device__ inline float leaky(float x) { return x >= 0.f ? x : 0.2f * x; }

__device__ inline int wave_incl_scan(int v) {
    int lane = threadIdx.x & 63;
#pragma unroll
    for (int d = 1; d < 64; d <<= 1) {
        int t = __shfl_up(v, d, 64);
        if (lane >= d) v += t;
    }
    return v;
}

__global__ __launch_bounds__(1024) void k_all(
    const float* __restrict__ x, const int* __restrict__ src, const int* __restrict__ dst,
    const float* __restrict__ W1, const float* __restrict__ b1,
    const float* __restrict__ Ws, const float* __restrict__ bs,
    const float* __restrict__ Wg, const float* __restrict__ a_srcw,
    const float* __restrict__ a_dstw, const float* __restrict__ bg,
    const float* __restrict__ Wf1, const float* __restrict__ bf1,
    const float* __restrict__ Wf2, const float* __restrict__ bf2,
    float* __restrict__ x1g, float* __restrict__ out)
{
    __shared__ char arena[ARENA_SZ];
    float*          h1L   = (float*)(arena + OFF_H1);
    float*          xpL   = (float*)(arena + OFF_XP);
    unsigned short* fadjL = (unsigned short*)(arena + OFF_FADJ);
    unsigned*       skL   = (unsigned*)(arena + OFF_SK);
    int*            newL  = (int*)(arena + OFF_NEWL);
    float*          scoreL= (float*)(arena + OFF_SCORE);
    unsigned short* permL = (unsigned short*)(arena + OFF_PERML);
    unsigned short* csrL  = (unsigned short*)(arena + OFF_CSR);
    int*            hist  = (int*)(arena + OFF_HIST);
    int*            rsL   = (int*)(arena + OFF_RS);
    float*          dinvL = (float*)(arena + OFF_DINV);
    float*          hsL   = (float*)(arena + OFF_HS);
    float*          hfL   = (float*)(arena + OFF_HF);
    float*          alsL  = (float*)(arena + OFF_ALS);
    float*          aldL  = (float*)(arena + OFF_ALD);
    int*            fcntL = (int*)(arena + OFF_FCNT);
    float*          wred  = (float*)(arena + OFF_WRED);
    float*          goutL = (float*)(arena + OFF_GOUT);
    float*          hidL  = (float*)(arena + OFF_HID);
    int*            wsumL = (int*)(arena + OFF_WSUM);
    int*            flags = (int*)(arena + OFF_FLAGS);
#define bselS  flags[0]
#define bneedS flags[1]
#define curS   flags[2]
#define totS   flags[3]

    int g = blockIdx.x, tid = threadIdx.x, wid = tid >> 6;
    int nbase = g * NPG, ebase = g * EPG;

    // ---- Phase A: zero hist; h1 = x @ W1 into LDS
    for (int i = tid; i < NPG; i += 1024) hist[i] = 0;
    for (int i = tid; i < NPG; i += 1024) {
        float xi[5];
#pragma unroll
        for (int k = 0; k < 5; k++) xi[k] = x[(size_t)(nbase + i) * 5 + k];
#pragma unroll
        for (int j = 0; j < 10; j++) {
            float s = 0.f;
#pragma unroll
            for (int k = 0; k < 5; k++) s += xi[k] * W1[k * 10 + j];
            h1L[i * 10 + j] = s;
        }
    }
    __syncthreads();
    for (int e = tid; e < EPG; e += 1024)
        atomicAdd(&hist[dst[ebase + e] - nbase], 1);
    __syncthreads();
    // exclusive scan (2 bins/thread, 16 wave partials)
    {
        int b2 = tid * 2;
        int v0 = hist[b2], v1 = hist[b2 + 1];
        int s = v0 + v1;
        int incl = wave_incl_scan(s);
        if ((tid & 63) == 63) wsumL[wid] = incl;
        __syncthreads();
        if (tid == 0) {
            int a = 0;
#pragma unroll
            for (int w = 0; w < 16; w++) { int t = wsumL[w]; wsumL[w] = a; a += t; }
            rsL[NPG] = EPG;
        }
        __syncthreads();
        int base = wsumL[wid] + incl - s;
        rsL[b2] = base;
        rsL[b2 + 1] = base + v0;
        dinvL[b2] = rsqrtf((float)v0 + 1.0f);
        dinvL[b2 + 1] = rsqrtf((float)v1 + 1.0f);
        hist[b2] = 0; hist[b2 + 1] = 0;          // cursors
    }
    __syncthreads();
    for (int e = tid; e < EPG; e += 1024) {
        int ee = ebase + e;
        int sl = src[ee] - nbase;
        int dl = dst[ee] - nbase;
        int pos = rsL[dl] + atomicAdd(&hist[dl], 1);
        csrL[pos] = (unsigned short)sl;
    }
    __syncthreads();

    // ---- Phase B: GCN10 gather from LDS; x1 -> global; hs -> LDS
    for (int i = tid; i < NPG; i += 1024) {
        float di = dinvL[i];
        float acc[10];
#pragma unroll
        for (int j = 0; j < 10; j++) acc[j] = 0.f;
        int p0 = rsL[i], p1 = rsL[i + 1];
        for (int e = p0; e < p1; e++) {
            int s = csrL[e];
            float dv = dinvL[s];
#pragma unroll
            for (int j = 0; j < 10; j++) acc[j] += h1L[s * 10 + j] * dv;
        }
        float d2 = di * di;
        float dot = 0.f;
#pragma unroll
        for (int j = 0; j < 10; j++) {
            float v = acc[j] * di + h1L[i * 10 + j] * d2 + b1[j];
            x1g[(size_t)(nbase + i) * 10 + j] = v;
            dot += v * Ws[j];
        }
        hsL[i] = dot;
    }
    __syncthreads();

    // ---- Phase C: scorer GCN from LDS -> scoreL, monotone keys; init topk state
    float bsv = bs[0];
    for (int i = tid; i < NPG; i += 1024) {
        float di = dinvL[i];
        int p0 = rsL[i], p1 = rsL[i + 1];
        float a = 0.f;
        for (int e = p0; e < p1; e++) {
            int s = csrL[e];
            a += dinvL[s] * hsL[s];
        }
        float sc = di * a + hsL[i] * di * di + bsv;
        scoreL[i] = sc;
        unsigned u = __float_as_uint(sc);
        skL[i] = (u & 0x80000000u) ? ~u : (u | 0x80000000u);
        newL[i] = -1;
        hist[i] = 0;                              // bins
    }
    if (tid == 0) curS = 0;
    int need = KSEL;
    unsigned prefix = 0;
    __syncthreads();

    // ---- Phase D: 3-level radix select (11/11/10 bits)
    for (int lv = 0; lv < 3; lv++) {
        for (int i = tid; i < NPG; i += 1024) {
            unsigned k = skL[i];
            bool match; unsigned bb;
            if (lv == 0)      { match = true;                  bb = k >> 21; }
            else if (lv == 1) { match = ((k >> 21) == prefix); bb = (k >> 10) & 0x7FFu; }
            else              { match = ((k >> 10) == prefix); bb = k & 0x3FFu; }
            if (match) atomicAdd(&hist[bb], 1);
        }
        __syncthreads();
        int b2 = tid * 2;
        int v0 = hist[b2], v1 = hist[b2 + 1];
        hist[b2] = 0; hist[b2 + 1] = 0;
        int s = v0 + v1;
        int incl = wave_incl_scan(s);
        if ((tid & 63) == 63) wsumL[wid] = incl;
        __syncthreads();
        if (tid == 0) {
            int a = 0;
#pragma unroll
            for (int w = 0; w < 16; w++) { int t = wsumL[w]; wsumL[w] = a; a += t; }
            totS = a;
        }
        __syncthreads();
        int base = wsumL[wid] + incl - s;
        int tot = totS;
        { int Sb = tot - base;        int Sb1 = Sb - v0; if (Sb >= need && Sb1 < need) { bselS = b2;     bneedS = need - Sb1; } }
        { int Sb = tot - (base + v0); int Sb1 = Sb - v1; if (Sb >= need && Sb1 < need) { bselS = b2 + 1; bneedS = need - Sb1; } }
        __syncthreads();
        if (lv == 0)      prefix = (unsigned)bselS;
        else if (lv == 1) prefix = (prefix << 11) | (unsigned)bselS;
        else              prefix = (prefix << 10) | (unsigned)bselS;
        need = bneedS;
        __syncthreads();
    }
    unsigned T = prefix;              // exact K-th largest key; need = #ties to take
    int greaterCnt = KSEL - need;

    for (int i = tid; i < NPG; i += 1024) {
        if (skL[i] > T) {
            int p = atomicAdd(&curS, 1);
            permL[p] = (unsigned short)i;
            newL[i] = p;
        }
    }
    {   // ties == T: lowest indices first
        int b2 = tid * 2;
        int lc = 0, loc2[2];
#pragma unroll
        for (int k = 0; k < 2; k++)
            if (skL[b2 + k] == T) loc2[lc++] = b2 + k;
        __syncthreads();
        int incl = wave_incl_scan(lc);
        if ((tid & 63) == 63) wsumL[wid] = incl;
        __syncthreads();
        if (tid == 0) {
            int a = 0;
#pragma unroll
            for (int w = 0; w < 16; w++) { int t = wsumL[w]; wsumL[w] = a; a += t; }
        }
        __syncthreads();
        int rank0 = wsumL[wid] + incl - lc;
        for (int j = 0; j < lc; j++) {
            int rank = rank0 + j;
            if (rank < need) {
                int p = greaterCnt + rank;
                permL[p] = (unsigned short)loc2[j];
                newL[loc2[j]] = p;
            }
        }
    }
    __syncthreads();

    // ---- Phase E: gated pooled features xp + filtered pooled adjacency
    for (int p = tid; p < KSEL; p += 1024) {
        int iL = permL[p];
        float tt = tanhf(scoreL[iL]);
#pragma unroll
        for (int k = 0; k < 10; k++)
            xpL[p * 10 + k] = x1g[(size_t)(nbase + iL) * 10 + k] * tt;
        int p0 = rsL[iL], p1 = rsL[iL + 1];
        int c = 0;
        for (int e = p0; e < p1; e++) {
            int s2 = newL[csrL[e]];
            if (s2 >= 0 && c < FCAP) fadjL[p * FCAP + c++] = (unsigned short)s2;
        }
        fcntL[p] = c;
    }
    __syncthreads();

    // ---- Phase F: GAT features per (p, head); hfL overwrites dead regions
    for (int t = tid; t < KSEL * NH; t += 1024) {
        int p = t / NH, hh = t - p * NH;
        float xi[10];
#pragma unroll
        for (int k = 0; k < 10; k++) xi[k] = xpL[p * 10 + k];
        float as_ = 0.f, ad_ = 0.f;
#pragma unroll
        for (int c = 0; c < NC; c++) {
            int j = hh * NC + c;
            float vv = 0.f;
#pragma unroll
            for (int k = 0; k < 10; k++) vv += xi[k] * Wg[k * HC + j];
            hfL[p * HC + j] = vv;
            as_ += vv * a_srcw[j];
            ad_ += vv * a_dstw[j];
        }
        alsL[p * NH + hh] = as_;
        aldL[p * NH + hh] = ad_;
    }
    __syncthreads();

    // ---- Phase G: softmax agg over filtered adjacency + butterfly readout
    {
        float res[NC];
        // round 1: tasks 0..1023 (hh = tid>>9 in {0,1}, p = tid & 511)
        {
            int hh = tid >> 9, p = tid & (KPAD - 1);
            if (p < KSEL) {
                float aldp = aldL[p * NH + hh];
                float lself = leaky(alsL[p * NH + hh] + aldp);
                float m = lself;
                int c = fcntL[p];
                const unsigned short* f = fadjL + p * FCAP;
                for (int e = 0; e < c; e++)
                    m = fmaxf(m, leaky(alsL[f[e] * NH + hh] + aldp));
                float wself = expf(lself - m), wsum = wself;
                const float* hp = hfL + p * HC + hh * NC;
#pragma unroll
                for (int cc = 0; cc < NC; cc++) res[cc] = wself * hp[cc];
                for (int e = 0; e < c; e++) {
                    int s2 = f[e];
                    float w = expf(leaky(alsL[s2 * NH + hh] + aldp) - m);
                    wsum += w;
                    const float* hq = hfL + s2 * HC + hh * NC;
#pragma unroll
                    for (int cc = 0; cc < NC; cc++) res[cc] += w * hq[cc];
                }
                float inv = 1.f / wsum;
#pragma unroll
                for (int cc = 0; cc < NC; cc++) res[cc] *= inv;
            } else {
#pragma unroll
                for (int cc = 0; cc < NC; cc++) res[cc] = 0.f;
            }
#pragma unroll
            for (int cc = 0; cc < NC; cc++) {
                float v = res[cc];
#pragma unroll
                for (int d = 1; d < 64; d <<= 1) v += __shfl_xor(v, d, 64);
                res[cc] = v;
            }
            if ((tid & 63) == 0) {
                int slot = hh * 8 + (wid & 7);
#pragma unroll
                for (int cc = 0; cc < NC; cc++) wred[slot * NC + cc] = res[cc];
            }
        }
        // round 2: tasks 1024..1535 (hh=2, p = tid), threads 0..511 only
        if (tid < KPAD) {
            int p = tid, hh = 2;
            if (p < KSEL) {
                float aldp = aldL[p * NH + hh];
                float lself = leaky(alsL[p * NH + hh] + aldp);
                float m = lself;
                int c = fcntL[p];
                const unsigned short* f = fadjL + p * FCAP;
                for (int e = 0; e < c; e++)
                    m = fmaxf(m, leaky(alsL[f[e] * NH + hh] + aldp));
                float wself = expf(lself - m), wsum = wself;
                const float* hp = hfL + p * HC + hh * NC;
#pragma unroll
                for (int cc = 0; cc < NC; cc++) res[cc] = wself * hp[cc];
                for (int e = 0; e < c; e++) {
                    int s2 = f[e];
                    float w = expf(leaky(alsL[s2 * NH + hh] + aldp) - m);
                    wsum += w;
                    const float* hq = hfL + s2 * HC + hh * NC;
#pragma unroll
                    for (int cc = 0; cc < NC; cc++) res[cc] += w * hq[cc];
                }
                float inv = 1.f / wsum;
#pragma unroll
                for (int cc = 0; cc < NC; cc++) res[cc] *= inv;
            } else {
#pragma unroll
                for (int cc = 0; cc < NC; cc++) res[cc] = 0.f;
            }
#pragma unroll
            for (int cc = 0; cc < NC; cc++) {
                float v = res[cc];
#pragma unroll
                for (int d = 1; d < 64; d <<= 1) v += __shfl_xor(v, d, 64);
                res[cc] = v;
            }
            if ((tid & 63) == 0) {
                int slot = 16 + wid;
#pragma unroll
                for (int cc = 0; cc < NC; cc++) wred[slot * NC + cc] = res[cc];
            }
        }
    }
    __syncthreads();
    if (tid < HC) {
        int hh = tid / NC, c = tid - hh * NC;
        float a = 0.f;
#pragma unroll
        for (int w = 0; w < 8; w++) a += wred[(hh * 8 + w) * NC + c];
        goutL[tid] = a + (float)KSEL * bg[tid];
    }
    __syncthreads();

    // ---- Phase H: MLP + log_softmax
    if (tid < 30) {
        float s = bf1[tid];
#pragma unroll
        for (int k = 0; k < HC; k++) s += goutL[k] * Wf1[k * 30 + tid];
        hidL[tid] = s > 0.f ? s : 0.f;
    }
    __syncthreads();
    if (tid == 0) {
        float z[3];
#pragma unroll
        for (int j = 0; j < 3; j++) {
            float s = bf2[j];
            for (int k = 0; k < 30; k++) s += hidL[k] * Wf2[k * 3 + j];
            z[j] = s;
        }
        float m = fmaxf(z[0], fmaxf(z[1], z[2]));
        float lse = logf(expf(z[0] - m) + expf(z[1] - m) + expf(z[2] - m)) + m;
#pragma unroll
        for (int j = 0; j < 3; j++) out[g * 3 + j] = z[j] - lse;
    }
}

extern "C" void kernel_launch(void* const* d_in, const int* in_sizes, int n_in,
                              void* d_out, int out_size, void* d_ws, size_t ws_size,
                              hipStream_t stream) {
    const float* x     = (const float*)d_in[0];
    const int*   src   = (const int*)d_in[1];
    const int*   dst   = (const int*)d_in[2];
    const float* W1    = (const float*)d_in[4];
    const float* b1    = (const float*)d_in[5];
    const float* Ws    = (const float*)d_in[6];
    const float* bs    = (const float*)d_in[7];
    const float* Wg    = (const float*)d_in[8];
    const float* a_src = (const float*)d_in[9];
    const float* a_dst = (const float*)d_in[10];
    const float* bg    = (const float*)d_in[11];
    const float* Wf1   = (const float*)d_in[12];
    const float* bf1   = (const float*)d_in[13];
    const float* Wf2   = (const float*)d_in[14];
    const float* bf2   = (const float*)d_in[15];
    float* out = (float*)d_out;

    float* x1g = (float*)d_ws;    // 10 * NTOT floats; fully overwritten each call

    k_all<<<G, 1024, 0, stream>>>(x, src, dst, W1, b1, Ws, bs, Wg, a_src, a_dst,
                                  bg, Wf1, bf1, Wf2, bf2, x1g, out);
}

// Round 11
// 143.453 us; speedup vs baseline: 1.3151x; 1.0793x over previous
//
#include <hip/hip_runtime.h>
#include <math.h>

#define G    64
#define NPG  2048
#define NTOT (G * NPG)          // 131072
#define EPG  (NPG * 8)          // 16384 edges per graph (contiguous by construction)
#define NE   (NTOT * 8)         // 1048576
#define KSEL 410
#define NH   3
#define NC   20
#define HC   60
#define FCAP 24
#define KPAD 512
#define RP   12                 // padded row: h1[0..9], dinv@10, hs@11 (48 B)

// ---- LDS arena (bytes). Lifetimes: A=csr build, B=gcn10, C=scorer, D=topk,
//      E=pool+fadj, F=gat feat, G=agg+readout, H=mlp.
#define OFF_H1P   0             // 98304  h1p 2048x12f            [A..C]
#define OFF_CSR   98304         // 32768  csr u16                 [A..E]
#define OFF_HIST  131072        // 8192   hist/bins int           [A..D]
#define OFF_RS    139264        // 8192   rs int                  [A..E]
#define OFF_SK    147456        // 8192   sk u32                  [C..E]
#define OFF_NEWL  155648        // 4096   newL u16                [C..E]
#define OFF_PERML 159744        // 824    permL u16               [D..E]
#define OFF_WSUM  160568        // 64
#define OFF_FLAGS 160632        // 16
#define ARENA_SZ  160648
// aliased into dead regions:
#define OFF_XP    0             // 16400  xp 410x10f              [E..F]  (h1p dead)
#define OFF_FADJ  16400         // 19680  fadj 410x24 u16         [E..G]
#define OFF_FCNT  36080         // 1648   fcnt int                [E..G]
#define OFF_HF    37728         // 98400  hf 410x60f              [F..G]  (h1p/csr/hist dead)
#define OFF_ALS   139264        // 4920   als                     [F..G]  (rs dead)
#define OFF_ALD   144184        // 4920   ald                     [F..G]  (sk dead)
#define OFF_WRED  149104        // 1920                           [G]
#define OFF_GOUT  151024        // 240                            [G..H]
#define OFF_HID   151264        // 120                            [H]

__device__ inline float leaky(float x) { return x >= 0.f ? x : 0.2f * x; }

__device__ inline int wave_incl_scan(int v) {
    int lane = threadIdx.x & 63;
#pragma unroll
    for (int d = 1; d < 64; d <<= 1) {
        int t = __shfl_up(v, d, 64);
        if (lane >= d) v += t;
    }
    return v;
}

__global__ __launch_bounds__(1024) void k_all(
    const float* __restrict__ x, const int* __restrict__ src, const int* __restrict__ dst,
    const float* __restrict__ W1, const float* __restrict__ b1,
    const float* __restrict__ Ws, const float* __restrict__ bs,
    const float* __restrict__ Wg, const float* __restrict__ a_srcw,
    const float* __restrict__ a_dstw, const float* __restrict__ bg,
    const float* __restrict__ Wf1, const float* __restrict__ bf1,
    const float* __restrict__ Wf2, const float* __restrict__ bf2,
    float* __restrict__ x1g, float* __restrict__ out)
{
    __shared__ __align__(16) char arena[ARENA_SZ];
    float*          h1p   = (float*)(arena + OFF_H1P);
    unsigned short* csrL  = (unsigned short*)(arena + OFF_CSR);
    int*            hist  = (int*)(arena + OFF_HIST);
    int*            rsL   = (int*)(arena + OFF_RS);
    unsigned*       skL   = (unsigned*)(arena + OFF_SK);
    unsigned short* newLs = (unsigned short*)(arena + OFF_NEWL);
    unsigned short* permL = (unsigned short*)(arena + OFF_PERML);
    int*            wsumL = (int*)(arena + OFF_WSUM);
    int*            flags = (int*)(arena + OFF_FLAGS);
    float*          xpL   = (float*)(arena + OFF_XP);
    unsigned short* fadjL = (unsigned short*)(arena + OFF_FADJ);
    int*            fcntL = (int*)(arena + OFF_FCNT);
    float*          hfL   = (float*)(arena + OFF_HF);
    float*          alsL  = (float*)(arena + OFF_ALS);
    float*          aldL  = (float*)(arena + OFF_ALD);
    float*          wred  = (float*)(arena + OFF_WRED);
    float*          goutL = (float*)(arena + OFF_GOUT);
    float*          hidL  = (float*)(arena + OFF_HID);
#define bselS  flags[0]
#define bneedS flags[1]
#define curS   flags[2]
#define totS   flags[3]

    int g = blockIdx.x, tid = threadIdx.x, wid = tid >> 6;
    int nbase = g * NPG, ebase = g * EPG;

    // ---- Phase A: zero hist; h1 -> LDS (padded rows, vector writes)
    for (int i = tid; i < NPG; i += 1024) hist[i] = 0;
    for (int i = tid; i < NPG; i += 1024) {
        float xi[5];
#pragma unroll
        for (int k = 0; k < 5; k++) xi[k] = x[(size_t)(nbase + i) * 5 + k];
        float v[10];
#pragma unroll
        for (int j = 0; j < 10; j++) {
            float s = 0.f;
#pragma unroll
            for (int k = 0; k < 5; k++) s += xi[k] * W1[k * 10 + j];
            v[j] = s;
        }
        float4* row = (float4*)(h1p + i * RP);
        row[0] = make_float4(v[0], v[1], v[2], v[3]);
        row[1] = make_float4(v[4], v[5], v[6], v[7]);
        row[2] = make_float4(v[8], v[9], 0.f, 0.f);   // slots 10/11 rewritten later
    }
    __syncthreads();
    for (int e = tid; e < EPG; e += 1024)
        atomicAdd(&hist[dst[ebase + e] - nbase], 1);
    __syncthreads();
    {   // exclusive scan (2 bins/thread, 16 wave partials); dinv -> row slot 10
        int b2 = tid * 2;
        int v0 = hist[b2], v1 = hist[b2 + 1];
        int s = v0 + v1;
        int incl = wave_incl_scan(s);
        if ((tid & 63) == 63) wsumL[wid] = incl;
        __syncthreads();
        if (tid == 0) {
            int a = 0;
#pragma unroll
            for (int w = 0; w < 16; w++) { int t = wsumL[w]; wsumL[w] = a; a += t; }
        }
        __syncthreads();
        int base = wsumL[wid] + incl - s;
        rsL[b2] = base;
        rsL[b2 + 1] = base + v0;
        h1p[b2 * RP + 10] = rsqrtf((float)v0 + 1.0f);
        h1p[(b2 + 1) * RP + 10] = rsqrtf((float)v1 + 1.0f);
        hist[b2] = 0; hist[b2 + 1] = 0;              // cursors
    }
    __syncthreads();
    for (int e = tid; e < EPG; e += 1024) {
        int ee = ebase + e;
        int sl = src[ee] - nbase;
        int dl = dst[ee] - nbase;
        int pos = rsL[dl] + atomicAdd(&hist[dl], 1);
        csrL[pos] = (unsigned short)sl;
    }
    __syncthreads();

    // ---- Phase B: GCN10 gather (vector LDS reads); x1 -> global (stride 12); hs -> slot 11
    for (int i = tid; i < NPG; i += 1024) {
        const float4* rowi = (const float4*)(h1p + i * RP);
        float4 s0 = rowi[0], s1 = rowi[1], s2 = rowi[2];
        float di = s2.z;
        float a0 = 0.f, a1 = 0.f, a2 = 0.f, a3 = 0.f, a4 = 0.f;
        float a5 = 0.f, a6 = 0.f, a7 = 0.f, a8 = 0.f, a9 = 0.f;
        int p0 = rsL[i], p1 = (i == NPG - 1) ? EPG : rsL[i + 1];
        for (int e = p0; e < p1; e++) {
            int s = csrL[e];
            const float4* rw = (const float4*)(h1p + s * RP);
            float4 r0 = rw[0], r1 = rw[1], r2 = rw[2];
            float dv = r2.z;
            a0 += r0.x * dv; a1 += r0.y * dv; a2 += r0.z * dv; a3 += r0.w * dv;
            a4 += r1.x * dv; a5 += r1.y * dv; a6 += r1.z * dv; a7 += r1.w * dv;
            a8 += r2.x * dv; a9 += r2.y * dv;
        }
        float d2 = di * di;
        float v[10];
        v[0] = a0 * di + s0.x * d2 + b1[0];
        v[1] = a1 * di + s0.y * d2 + b1[1];
        v[2] = a2 * di + s0.z * d2 + b1[2];
        v[3] = a3 * di + s0.w * d2 + b1[3];
        v[4] = a4 * di + s1.x * d2 + b1[4];
        v[5] = a5 * di + s1.y * d2 + b1[5];
        v[6] = a6 * di + s1.z * d2 + b1[6];
        v[7] = a7 * di + s1.w * d2 + b1[7];
        v[8] = a8 * di + s2.x * d2 + b1[8];
        v[9] = a9 * di + s2.y * d2 + b1[9];
        float dot = 0.f;
#pragma unroll
        for (int j = 0; j < 10; j++) dot += v[j] * Ws[j];
        float4* xr = (float4*)(x1g + (size_t)(nbase + i) * RP);
        xr[0] = make_float4(v[0], v[1], v[2], v[3]);
        xr[1] = make_float4(v[4], v[5], v[6], v[7]);
        xr[2] = make_float4(v[8], v[9], 0.f, 0.f);
        h1p[i * RP + 11] = dot;                       // hs
    }
    __syncthreads();

    // ---- Phase C: scorer gather ((dinv,hs) as one b64); keys; init topk state
    float bsv = bs[0];
    for (int i = tid; i < NPG; i += 1024) {
        float2 own = *(const float2*)(h1p + i * RP + 10);   // dinv, hs
        int p0 = rsL[i], p1 = (i == NPG - 1) ? EPG : rsL[i + 1];
        float a = 0.f;
        for (int e = p0; e < p1; e++) {
            float2 dh = *(const float2*)(h1p + csrL[e] * RP + 10);
            a += dh.x * dh.y;
        }
        float sc = own.x * a + own.y * own.x * own.x + bsv;
        unsigned u = __float_as_uint(sc);
        skL[i] = (u & 0x80000000u) ? ~u : (u | 0x80000000u);
        newLs[i] = 0xFFFFu;
        hist[i] = 0;
    }
    if (tid == 0) curS = 0;
    int need = KSEL;
    unsigned prefix = 0;
    __syncthreads();

    // ---- Phase D: 3-level radix select (11/11/10 bits)
    for (int lv = 0; lv < 3; lv++) {
        for (int i = tid; i < NPG; i += 1024) {
            unsigned k = skL[i];
            bool match; unsigned bb;
            if (lv == 0)      { match = true;                  bb = k >> 21; }
            else if (lv == 1) { match = ((k >> 21) == prefix); bb = (k >> 10) & 0x7FFu; }
            else              { match = ((k >> 10) == prefix); bb = k & 0x3FFu; }
            if (match) atomicAdd(&hist[bb], 1);
        }
        __syncthreads();
        int b2 = tid * 2;
        int v0 = hist[b2], v1 = hist[b2 + 1];
        hist[b2] = 0; hist[b2 + 1] = 0;
        int s = v0 + v1;
        int incl = wave_incl_scan(s);
        if ((tid & 63) == 63) wsumL[wid] = incl;
        __syncthreads();
        if (tid == 0) {
            int a = 0;
#pragma unroll
            for (int w = 0; w < 16; w++) { int t = wsumL[w]; wsumL[w] = a; a += t; }
            totS = a;
        }
        __syncthreads();
        int base = wsumL[wid] + incl - s;
        int tot = totS;
        { int Sb = tot - base;        int Sb1 = Sb - v0; if (Sb >= need && Sb1 < need) { bselS = b2;     bneedS = need - Sb1; } }
        { int Sb = tot - (base + v0); int Sb1 = Sb - v1; if (Sb >= need && Sb1 < need) { bselS = b2 + 1; bneedS = need - Sb1; } }
        __syncthreads();
        if (lv == 0)      prefix = (unsigned)bselS;
        else if (lv == 1) prefix = (prefix << 11) | (unsigned)bselS;
        else              prefix = (prefix << 10) | (unsigned)bselS;
        need = bneedS;
        __syncthreads();
    }
    unsigned T = prefix;              // exact K-th largest key; need = #ties to take
    int greaterCnt = KSEL - need;

    for (int i = tid; i < NPG; i += 1024) {
        if (skL[i] > T) {
            int p = atomicAdd(&curS, 1);
            permL[p] = (unsigned short)i;
            newLs[i] = (unsigned short)p;
        }
    }
    {   // ties == T: lowest indices first
        int b2 = tid * 2;
        int lc = 0, loc2[2];
#pragma unroll
        for (int k = 0; k < 2; k++)
            if (skL[b2 + k] == T) loc2[lc++] = b2 + k;
        __syncthreads();
        int incl = wave_incl_scan(lc);
        if ((tid & 63) == 63) wsumL[wid] = incl;
        __syncthreads();
        if (tid == 0) {
            int a = 0;
#pragma unroll
            for (int w = 0; w < 16; w++) { int t = wsumL[w]; wsumL[w] = a; a += t; }
        }
        __syncthreads();
        int rank0 = wsumL[wid] + incl - lc;
        for (int j = 0; j < lc; j++) {
            int rank = rank0 + j;
            if (rank < need) {
                int p = greaterCnt + rank;
                permL[p] = (unsigned short)loc2[j];
                newLs[loc2[j]] = (unsigned short)p;
            }
        }
    }
    __syncthreads();

    // ---- Phase E: gated pooled features (score from key inversion) + filtered adjacency
    for (int p = tid; p < KSEL; p += 1024) {
        int iL = permL[p];
        unsigned k = skL[iL];
        unsigned u = (k & 0x80000000u) ? (k & 0x7FFFFFFFu) : ~k;
        float tt = tanhf(__uint_as_float(u));
        const float4* xr = (const float4*)(x1g + (size_t)(nbase + iL) * RP);
        float4 q0 = xr[0], q1 = xr[1], q2 = xr[2];
        float* xp = xpL + p * 10;
        xp[0] = q0.x * tt; xp[1] = q0.y * tt; xp[2] = q0.z * tt; xp[3] = q0.w * tt;
        xp[4] = q1.x * tt; xp[5] = q1.y * tt; xp[6] = q1.z * tt; xp[7] = q1.w * tt;
        xp[8] = q2.x * tt; xp[9] = q2.y * tt;
        int p0 = rsL[iL], p1 = (iL == NPG - 1) ? EPG : rsL[iL + 1];
        int c = 0;
        for (int e = p0; e < p1; e++) {
            unsigned short s2 = newLs[csrL[e]];
            if (s2 != 0xFFFFu && c < FCAP) fadjL[p * FCAP + c++] = s2;
        }
        fcntL[p] = c;
    }
    __syncthreads();

    // ---- Phase F: GAT features per (p, head)
    for (int t = tid; t < KSEL * NH; t += 1024) {
        int p = t / NH, hh = t - p * NH;
        float xi[10];
#pragma unroll
        for (int k = 0; k < 10; k++) xi[k] = xpL[p * 10 + k];
        float v[NC];
        float as_ = 0.f, ad_ = 0.f;
#pragma unroll
        for (int c = 0; c < NC; c++) {
            int j = hh * NC + c;
            float vv = 0.f;
#pragma unroll
            for (int k = 0; k < 10; k++) vv += xi[k] * Wg[k * HC + j];
            v[c] = vv;
            as_ += vv * a_srcw[j];
            ad_ += vv * a_dstw[j];
        }
        float4* hr = (float4*)(hfL + p * HC + hh * NC);
#pragma unroll
        for (int q = 0; q < 5; q++)
            hr[q] = make_float4(v[4 * q], v[4 * q + 1], v[4 * q + 2], v[4 * q + 3]);
        alsL[p * NH + hh] = as_;
        aldL[p * NH + hh] = ad_;
    }
    __syncthreads();

    // ---- Phase G: softmax agg over filtered adjacency + butterfly readout
    {
        float res[NC];
#pragma unroll
        for (int rnd = 0; rnd < 2; rnd++) {
            int task = rnd == 0 ? tid : 1024 + tid;
            bool on = rnd == 0 || tid < KPAD;
            int hh = task >> 9, p = task & (KPAD - 1);
            if (on) {
                if (p < KSEL) {
                    float aldp = aldL[p * NH + hh];
                    float lself = leaky(alsL[p * NH + hh] + aldp);
                    float m = lself;
                    int c = fcntL[p];
                    const unsigned short* f = fadjL + p * FCAP;
                    for (int e = 0; e < c; e++)
                        m = fmaxf(m, leaky(alsL[f[e] * NH + hh] + aldp));
                    float wself = expf(lself - m), wsum = wself;
                    const float4* hp = (const float4*)(hfL + p * HC + hh * NC);
                    float4 r0 = hp[0], r1 = hp[1], r2 = hp[2], r3 = hp[3], r4 = hp[4];
                    r0.x *= wself; r0.y *= wself; r0.z *= wself; r0.w *= wself;
                    r1.x *= wself; r1.y *= wself; r1.z *= wself; r1.w *= wself;
                    r2.x *= wself; r2.y *= wself; r2.z *= wself; r2.w *= wself;
                    r3.x *= wself; r3.y *= wself; r3.z *= wself; r3.w *= wself;
                    r4.x *= wself; r4.y *= wself; r4.z *= wself; r4.w *= wself;
                    for (int e = 0; e < c; e++) {
                        int s2 = f[e];
                        float w = expf(leaky(alsL[s2 * NH + hh] + aldp) - m);
                        wsum += w;
                        const float4* hq = (const float4*)(hfL + s2 * HC + hh * NC);
                        float4 t0 = hq[0], t1 = hq[1], t2 = hq[2], t3 = hq[3], t4 = hq[4];
                        r0.x += w * t0.x; r0.y += w * t0.y; r0.z += w * t0.z; r0.w += w * t0.w;
                        r1.x += w * t1.x; r1.y += w * t1.y; r1.z += w * t1.z; r1.w += w * t1.w;
                        r2.x += w * t2.x; r2.y += w * t2.y; r2.z += w * t2.z; r2.w += w * t2.w;
                        r3.x += w * t3.x; r3.y += w * t3.y; r3.z += w * t3.z; r3.w += w * t3.w;
                        r4.x += w * t4.x; r4.y += w * t4.y; r4.z += w * t4.z; r4.w += w * t4.w;
                    }
                    float inv = 1.f / wsum;
                    res[0] = r0.x * inv; res[1] = r0.y * inv; res[2] = r0.z * inv; res[3] = r0.w * inv;
                    res[4] = r1.x * inv; res[5] = r1.y * inv; res[6] = r1.z * inv; res[7] = r1.w * inv;
                    res[8] = r2.x * inv; res[9] = r2.y * inv; res[10] = r2.z * inv; res[11] = r2.w * inv;
                    res[12] = r3.x * inv; res[13] = r3.y * inv; res[14] = r3.z * inv; res[15] = r3.w * inv;
                    res[16] = r4.x * inv; res[17] = r4.y * inv; res[18] = r4.z * inv; res[19] = r4.w * inv;
                } else {
#pragma unroll
                    for (int cc = 0; cc < NC; cc++) res[cc] = 0.f;
                }
#pragma unroll
                for (int cc = 0; cc < NC; cc++) {
                    float v = res[cc];
#pragma unroll
                    for (int d = 1; d < 64; d <<= 1) v += __shfl_xor(v, d, 64);
                    res[cc] = v;
                }
                if ((tid & 63) == 0) {
                    int slot = rnd == 0 ? hh * 8 + (wid & 7) : 16 + wid;
#pragma unroll
                    for (int cc = 0; cc < NC; cc++) wred[slot * NC + cc] = res[cc];
                }
            }
        }
    }
    __syncthreads();
    if (tid < HC) {
        int hh = tid / NC, c = tid - hh * NC;
        float a = 0.f;
#pragma unroll
        for (int w = 0; w < 8; w++) a += wred[(hh * 8 + w) * NC + c];
        goutL[tid] = a + (float)KSEL * bg[tid];
    }
    __syncthreads();

    // ---- Phase H: MLP + log_softmax
    if (tid < 30) {
        float s = bf1[tid];
#pragma unroll
        for (int k = 0; k < HC; k++) s += goutL[k] * Wf1[k * 30 + tid];
        hidL[tid] = s > 0.f ? s : 0.f;
    }
    __syncthreads();
    if (tid == 0) {
        float z[3];
#pragma unroll
        for (int j = 0; j < 3; j++) {
            float s = bf2[j];
            for (int k = 0; k < 30; k++) s += hidL[k] * Wf2[k * 3 + j];
            z[j] = s;
        }
        float m = fmaxf(z[0], fmaxf(z[1], z[2]));
        float lse = logf(expf(z[0] - m) + expf(z[1] - m) + expf(z[2] - m)) + m;
#pragma unroll
        for (int j = 0; j < 3; j++) out[g * 3 + j] = z[j] - lse;
    }
}

extern "C" void kernel_launch(void* const* d_in, const int* in_sizes, int n_in,
                              void* d_out, int out_size, void* d_ws, size_t ws_size,
                              hipStream_t stream) {
    const float* x     = (const float*)d_in[0];
    const int*   src   = (const int*)d_in[1];
    const int*   dst   = (const int*)d_in[2];
    const float* W1    = (const float*)d_in[4];
    const float* b1    = (const float*)d_in[5];
    const float* Ws    = (const float*)d_in[6];
    const float* bs    = (const float*)d_in[7];
    const float* Wg    = (const float*)d_in[8];
    const float* a_src = (const float*)d_in[9];
    const float* a_dst = (const float*)d_in[10];
    const float* bg    = (const float*)d_in[11];
    const float* Wf1   = (const float*)d_in[12];
    const float* bf1   = (const float*)d_in[13];
    const float* Wf2   = (const float*)d_in[14];
    const float* bf2   = (const float*)d_in[15];
    float* out = (float*)d_out;

    float* x1g = (float*)d_ws;    // 12 * NTOT floats (padded rows); overwritten each call

    k_all<<<G, 1024, 0, stream>>>(x, src, dst, W1, b1, Ws, bs, Wg, a_src, a_dst,
                                  bg, Wf1, bf1, Wf2, bf2, x1g, out);
}